// Round 9
// baseline (216.563 us; speedup 1.0000x reference)
//
#include <hip/hip_runtime.h>

typedef __attribute__((ext_vector_type(8))) short short8;
typedef __attribute__((ext_vector_type(4))) float f32x4;
typedef __attribute__((ext_vector_type(4))) unsigned short u16x4;

#define MFMA_BF16(a, b, c) __builtin_amdgcn_mfma_f32_16x16x32_bf16((a), (b), (c), 0, 0, 0)

__device__ __forceinline__ unsigned short f2bf(float f) {
  unsigned int u = __builtin_bit_cast(unsigned int, f);
  u += 0x7fffu + ((u >> 16) & 1u);
  return (unsigned short)(u >> 16);
}

__device__ __forceinline__ float bf2f(unsigned short s) {
  unsigned int u = ((unsigned int)s) << 16;
  return __builtin_bit_cast(float, u);
}

// async global->LDS, 16 bytes per lane; LDS dest = wave-uniform base + lane*16
__device__ __forceinline__ void gload_lds16(const void* g, void* lds) {
  __builtin_amdgcn_global_load_lds(
      (const __attribute__((address_space(1))) unsigned int*)g,
      (__attribute__((address_space(3))) unsigned int*)lds, 16, 0, 0);
}

// ---------------- fused cast f32 -> bf16 for x + 5 weight matrices ----------------
__global__ __launch_bounds__(256) void cast_all(const float* __restrict__ x,
                                                const float* __restrict__ Wq,
                                                const float* __restrict__ Wk,
                                                const float* __restrict__ Wv,
                                                const float* __restrict__ Wo,
                                                const float* __restrict__ Wf,
                                                unsigned short* __restrict__ xb,
                                                unsigned short* __restrict__ Wqkv,
                                                unsigned short* __restrict__ Wob,
                                                unsigned short* __restrict__ Wfb) {
  int i = blockIdx.x * 256 + threadIdx.x;
  const float* src;
  unsigned short* dst;
  int j;
  if (i < 1048576)      { src = x;  dst = xb;             j = i; }
  else if (i < 1310720) { src = Wq; dst = Wqkv;           j = i - 1048576; }
  else if (i < 1572864) { src = Wk; dst = Wqkv + 1048576; j = i - 1310720; }
  else if (i < 1835008) { src = Wv; dst = Wqkv + 2097152; j = i - 1572864; }
  else if (i < 2097152) { src = Wo; dst = Wob;            j = i - 1835008; }
  else                  { src = Wf; dst = Wfb;            j = i - 2097152; }
  float4 v = ((const float4*)src)[j];
  u16x4 r = { f2bf(v.x), f2bf(v.y), f2bf(v.z), f2bf(v.w) };
  ((u16x4*)dst)[j] = r;
}

// ---------------- GEMM (m97 structure): C[M,N] = A[M,K] * W[N,K]^T + bias ----------------
template <int EPI>
__global__ __launch_bounds__(256) void gemm_lds(const unsigned short* __restrict__ A,
                                                const unsigned short* __restrict__ W,
                                                const float* __restrict__ bias,
                                                void* __restrict__ Cout,
                                                int M, int N, int K) {
  __shared__ unsigned short At[128 * 32];
  __shared__ unsigned short Bt[128 * 32];

  const int tid = threadIdx.x;
  const int w = tid >> 6, l = tid & 63;
  const int lr = l & 15, lq = l >> 4;
  const int wr = w >> 1, wc = w & 1;
  const int row0 = blockIdx.x * 128;
  const int col0 = blockIdx.y * 128;

  const int srow = l >> 2;
  const int skoff = (l & 3) * 8;

  f32x4 acc[4][4] = {};

  const unsigned short* Abase = A + (row0 + srow) * (size_t)K + skoff;
  const unsigned short* Bbase = W + (col0 + srow) * (size_t)K + skoff;

  for (int kt = 0; kt < K; kt += 32) {
#pragma unroll
    for (int j = 0; j < 2; j++) {
      const int c = w * 2 + j;
      gload_lds16(Abase + (size_t)(c * 16) * K + kt, &At[c * 512]);
      gload_lds16(Bbase + (size_t)(c * 16) * K + kt, &Bt[c * 512]);
    }
    __syncthreads();

    short8 af[4], bfr[4];
#pragma unroll
    for (int m = 0; m < 4; m++)
      af[m] = *(const short8*)&At[(wr * 64 + m * 16 + lr) * 32 + lq * 8];
#pragma unroll
    for (int n = 0; n < 4; n++)
      bfr[n] = *(const short8*)&Bt[(wc * 64 + n * 16 + lr) * 32 + lq * 8];
#pragma unroll
    for (int m = 0; m < 4; m++)
#pragma unroll
      for (int n = 0; n < 4; n++)
        acc[m][n] = MFMA_BF16(af[m], bfr[n], acc[m][n]);
    __syncthreads();
  }

#pragma unroll
  for (int n = 0; n < 4; n++) {
    const int col = col0 + wc * 64 + n * 16 + lr;
    const float bv = bias[col];
#pragma unroll
    for (int m = 0; m < 4; m++) {
      const int row = row0 + wr * 64 + m * 16 + lq * 4;
#pragma unroll
      for (int r = 0; r < 4; r++) {
        float v = acc[m][n][r] + bv;
        if (EPI == 0) {
          ((unsigned short*)Cout)[(size_t)(row + r) * N + col] = f2bf(v);
        } else if (EPI == 1) {
          ((float*)Cout)[(size_t)(row + r) * N + col] = v;
        } else {
          float g = 0.5f * v * (1.0f + erff(v * 0.70710678118654752f));
          ((float*)Cout)[(size_t)(row + r) * N + col] = g;
        }
      }
    }
  }
}

// ---------------- maskadd (log2 domain): ma[b][k] = mask ? 0 : -1e10*log2e ----------------
__global__ __launch_bounds__(256) void maskadd_kernel(const int* __restrict__ mask,
                                                      float* __restrict__ ma) {
  int i = blockIdx.x * 256 + threadIdx.x;
  if (i < 4096) ma[i] = (mask[i] == 0) ? -1.4426950408889634e10f : 0.0f;
}

// ---------------- V transpose: VT[(bh*64+d)][k] <- v-slab of qkv ----------------
__global__ __launch_bounds__(256) void vtrans_kernel(const unsigned short* __restrict__ qkv,
                                                     unsigned short* __restrict__ VT) {
  const int bh = blockIdx.x;   // 64
  const int kt = blockIdx.y;   // 16 tiles of 64 keys
  const int t = threadIdx.x;
  const int d = t & 63, kg = t >> 6;
  const unsigned short* basev =
      qkv + ((size_t)(bh >> 4) * 1024 + (bh & 15) * 64) * 3072 + 2048;
  const unsigned short* src = basev + (size_t)(kt * 4 + kg) * 3072 + d;
  unsigned short vals[16];
#pragma unroll
  for (int j = 0; j < 16; j++) vals[j] = src[j * 64];
  short8 v0, v1;
#pragma unroll
  for (int j = 0; j < 8; j++) { v0[j] = (short)vals[j]; v1[j] = (short)vals[8 + j]; }
  size_t dst = ((size_t)bh * 64 + d) * 1024 + kt * 64 + kg * 16;
  *(short8*)&VT[dst] = v0;
  *(short8*)&VT[dst + 8] = v1;
}

// ---------------- flash attention v7: attn6 math + K-split x2 (no VGPR cap) ----------------
struct Frags {
  short8 kf[2][2];   // [key-half][d-chunk]
  short8 vf[4];      // V^T frags per d-tile
};

__device__ __forceinline__ void load_frags(Frags& f, int kt,
                                           const unsigned short* __restrict__ basek,
                                           const unsigned short* __restrict__ vtb,
                                           int lr, int lq) {
#pragma unroll
  for (int t = 0; t < 2; t++) {
    const unsigned short* ka = basek + (size_t)(kt * 2 + t) * 3072 + lr * 64;
    f.kf[t][0] = *(const short8*)(ka + lq * 8);
    f.kf[t][1] = *(const short8*)(ka + 32 + lq * 8);
  }
#pragma unroll
  for (int n = 0; n < 4; n++)
    f.vf[n] = *(const short8*)(vtb + (size_t)(n * 16 + lr) * 1024 + kt * 32 + lq * 8);
}

__device__ __forceinline__ void process(const Frags& f, int kcur, const short8 qf[2][2],
                                        const float* __restrict__ ma_lds,
                                        unsigned short* pw0, unsigned short* pw1,
                                        float m[2], float ll[2], f32x4 o[2][4],
                                        int lr, int lq) {
  constexpr float SC = 0.18033688011112042f;  // 0.125 * log2(e)
  unsigned short* pws[2] = {pw0, pw1};
  const float4 mk0 = *(const float4*)&ma_lds[kcur * 32 + lq * 4];
  const float4 mk1 = *(const float4*)&ma_lds[kcur * 32 + 16 + lq * 4];
#pragma unroll
  for (int qt2 = 0; qt2 < 2; qt2++) {
    // S^T tiles: rows = keys (lq*4+r [+16]), cols = q (lr)
    f32x4 s0 = {0.f, 0.f, 0.f, 0.f}, s1 = {0.f, 0.f, 0.f, 0.f};
    s0 = MFMA_BF16(f.kf[0][0], qf[qt2][0], s0);
    s0 = MFMA_BF16(f.kf[0][1], qf[qt2][1], s0);
    s1 = MFMA_BF16(f.kf[1][0], qf[qt2][0], s1);
    s1 = MFMA_BF16(f.kf[1][1], qf[qt2][1], s1);
    float sv[8];
#pragma unroll
    for (int r = 0; r < 4; r++) {
      sv[r]     = s0[r] * SC + ((const float*)&mk0)[r];
      sv[4 + r] = s1[r] * SC + ((const float*)&mk1)[r];
    }
    // online softmax (exp2 domain): state lane-local for q = lr; max over lq group
    float t = fmaxf(fmaxf(fmaxf(sv[0], sv[1]), fmaxf(sv[2], sv[3])),
                    fmaxf(fmaxf(sv[4], sv[5]), fmaxf(sv[6], sv[7])));
    t = fmaxf(t, __shfl_xor(t, 16));
    t = fmaxf(t, __shfl_xor(t, 32));
    float mn = fmaxf(m[qt2], t);
    float sc = __builtin_amdgcn_exp2f(m[qt2] - mn);
    m[qt2] = mn;
    float p[8], rs = 0.f;
#pragma unroll
    for (int i = 0; i < 8; i++) { p[i] = __builtin_amdgcn_exp2f(sv[i] - mn); rs += p[i]; }
    // deferred l-reduction: ll stays lane-partial (this lane's 8 keys); sc is group-uniform
    ll[qt2] = ll[qt2] * sc + rs;
    // pack P (bf16) to per-wave LDS: P[q=lr][k_local], stride 40
    uint2 wa, wb;
    wa.x = (unsigned)f2bf(p[0]) | ((unsigned)f2bf(p[1]) << 16);
    wa.y = (unsigned)f2bf(p[2]) | ((unsigned)f2bf(p[3]) << 16);
    wb.x = (unsigned)f2bf(p[4]) | ((unsigned)f2bf(p[5]) << 16);
    wb.y = (unsigned)f2bf(p[6]) | ((unsigned)f2bf(p[7]) << 16);
    *(uint2*)&pws[qt2][lr * 40 + lq * 4] = wa;
    *(uint2*)&pws[qt2][lr * 40 + 16 + lq * 4] = wb;
    // rescale O (rows q = lq*4+r use sc of lane lq*4+r)
    float scr[4];
#pragma unroll
    for (int r = 0; r < 4; r++) scr[r] = __shfl(sc, lq * 4 + r);
#pragma unroll
    for (int n = 0; n < 4; n++)
#pragma unroll
      for (int r = 0; r < 4; r++) o[qt2][n][r] *= scr[r];
  }
  asm volatile("s_waitcnt lgkmcnt(0)" ::: "memory");
  // PV: A = P[q=lr][k=lq*8..+7] (b128 from LDS), B = V^T frags
#pragma unroll
  for (int qt2 = 0; qt2 < 2; qt2++) {
    const short8 pa = *(const short8*)&pws[qt2][lr * 40 + lq * 8];
#pragma unroll
    for (int n = 0; n < 4; n++)
      o[qt2][n] = MFMA_BF16(pa, f.vf[n], o[qt2][n]);
  }
}

__global__ __launch_bounds__(256) void attn7_kernel(const unsigned short* __restrict__ qkv,
                                                    const unsigned short* __restrict__ VT,
                                                    const float* __restrict__ maskadd,
                                                    unsigned short* __restrict__ O0,
                                                    unsigned short* __restrict__ O1,
                                                    float2* __restrict__ ML) {
  __shared__ float ma_lds[1024];
  __shared__ unsigned short Pl[4][2][640];  // per wave, per q-tile: [16 q][40]

  const int bh = blockIdx.x, b = bh >> 4, h = bh & 15;
  const int qb = blockIdx.y;      // 0..7
  const int split = blockIdx.z;   // 0..1
  const int k0 = split * 16;      // 16 tiles of 32 keys per split
  const int tid = threadIdx.x, w = tid >> 6, l = tid & 63;
  const int lr = l & 15, lq = l >> 4;

  const unsigned short* baseq = qkv + ((size_t)b * 1024 + h * 64) * 3072;
  const unsigned short* basek = baseq + 1024;
  const unsigned short* vtb = VT + (size_t)bh * 64 * 1024;
  unsigned short* opart = split ? O1 : O0;

  // stage scaled mask row into LDS once
  ((float4*)ma_lds)[tid] = ((const float4*)(maskadd + b * 1024))[tid];
  __syncthreads();

  // Q fragments (2 tiles x 2 d-chunks), resident all kernel
  short8 qf[2][2];
  const int q0 = qb * 128 + w * 32;
#pragma unroll
  for (int t = 0; t < 2; t++) {
    int p = q0 + t * 16 + lr;
    const unsigned short* qa = baseq + (p >> 4) * 3072 + (p & 15) * 64;
    qf[t][0] = *(const short8*)(qa + lq * 8);
    qf[t][1] = *(const short8*)(qa + 32 + lq * 8);
  }

  float m[2] = {-1e30f, -1e30f}, ll[2] = {0.f, 0.f};
  f32x4 o[2][4] = {};

  unsigned short* pw0 = &Pl[w][0][0];
  unsigned short* pw1 = &Pl[w][1][0];

  Frags fa, fb;
  load_frags(fa, k0, basek, vtb, lr, lq);
#pragma unroll 1
  for (int lt = 0; lt < 16; lt += 2) {
    load_frags(fb, k0 + ((lt + 1) & 15), basek, vtb, lr, lq);
    process(fa, k0 + lt, qf, ma_lds, pw0, pw1, m, ll, o, lr, lq);
    load_frags(fa, k0 + ((lt + 2) & 15), basek, vtb, lr, lq);
    process(fb, k0 + lt + 1, qf, ma_lds, pw0, pw1, m, ll, o, lr, lq);
  }

  // epilogue: finish deferred l-reduction, write normalized O + (m,l)
#pragma unroll
  for (int qt2 = 0; qt2 < 2; qt2++) {
    float lf = ll[qt2];
    lf += __shfl_xor(lf, 16);
    lf += __shfl_xor(lf, 32);
    float inv[4];
#pragma unroll
    for (int r = 0; r < 4; r++) inv[r] = 1.0f / __shfl(lf, lq * 4 + r);
#pragma unroll
    for (int r = 0; r < 4; r++) {
      int q = q0 + qt2 * 16 + lq * 4 + r;
      size_t obase = ((size_t)b * 1024 + q) * 1024 + h * 64;
#pragma unroll
      for (int n = 0; n < 4; n++)
        opart[obase + n * 16 + lr] = f2bf(o[qt2][n][r] * inv[r]);
    }
    if (l < 16) {
      float2* mlrow = ML + ((size_t)split * 64 + bh) * 1024;
      mlrow[q0 + qt2 * 16 + l] = float2{m[qt2], lf};
    }
  }
}

// ---------------- combine the two K-splits ----------------
__global__ __launch_bounds__(256) void combine_kernel(const unsigned short* __restrict__ O0,
                                                      const unsigned short* __restrict__ O1,
                                                      const float2* __restrict__ ML,
                                                      unsigned short* __restrict__ att) {
  const int row = blockIdx.x;          // b*1024 + q
  const int t = threadIdx.x;
  const int col = t * 4;
  const int b = row >> 10, q = row & 1023;
  const int h = col >> 6;
  const int bh = b * 16 + h;
  const float2 ml0 = ML[(size_t)bh * 1024 + q];
  const float2 ml1 = ML[((size_t)64 + bh) * 1024 + q];
  const float M = fmaxf(ml0.x, ml1.x);
  float w0 = __builtin_amdgcn_exp2f(ml0.x - M) * ml0.y;
  float w1 = __builtin_amdgcn_exp2f(ml1.x - M) * ml1.y;
  const float inv = 1.0f / (w0 + w1);
  w0 *= inv; w1 *= inv;
  const size_t base = (size_t)row * 1024 + col;
  u16x4 a = *(const u16x4*)&O0[base];
  u16x4 c = *(const u16x4*)&O1[base];
  u16x4 r;
#pragma unroll
  for (int j = 0; j < 4; j++)
    r[j] = f2bf(bf2f(a[j]) * w0 + bf2f(c[j]) * w1);
  *(u16x4*)&att[base] = r;
}

// ---------------- LayerNorm kernels (fp32, E=1024, one row per block) ----------------
__global__ __launch_bounds__(256) void ln1_kernel(const float* __restrict__ x,
                                                  const float* __restrict__ attp,
                                                  const float* __restrict__ g,
                                                  const float* __restrict__ bt,
                                                  float* __restrict__ sf,
                                                  unsigned short* __restrict__ sb) {
  const int row = blockIdx.x, tid = threadIdx.x;
  float4 xv = ((const float4*)(x + row * 1024))[tid];
  float4 av = ((const float4*)(attp + row * 1024))[tid];
  float4 v = {xv.x + av.x, xv.y + av.y, xv.z + av.z, xv.w + av.w};
  float s = v.x + v.y + v.z + v.w;
  float sq = v.x * v.x + v.y * v.y + v.z * v.z + v.w * v.w;
#pragma unroll
  for (int off = 1; off < 64; off <<= 1) { s += __shfl_xor(s, off); sq += __shfl_xor(sq, off); }
  __shared__ float ws[8];
  int wv = tid >> 6, l = tid & 63;
  if (l == 0) { ws[wv] = s; ws[4 + wv] = sq; }
  __syncthreads();
  s = ws[0] + ws[1] + ws[2] + ws[3];
  sq = ws[4] + ws[5] + ws[6] + ws[7];
  float mean = s * (1.0f / 1024.0f);
  float var = sq * (1.0f / 1024.0f) - mean * mean;
  float rs = rsqrtf(var + 1e-5f);
  float4 gv = ((const float4*)g)[tid];
  float4 bv = ((const float4*)bt)[tid];
  float4 y;
  y.x = (v.x - mean) * rs * gv.x + bv.x;
  y.y = (v.y - mean) * rs * gv.y + bv.y;
  y.z = (v.z - mean) * rs * gv.z + bv.z;
  y.w = (v.w - mean) * rs * gv.w + bv.w;
  ((float4*)(sf + row * 1024))[tid] = y;
  u16x4 yb = { f2bf(y.x), f2bf(y.y), f2bf(y.z), f2bf(y.w) };
  ((u16x4*)(sb + row * 1024))[tid] = yb;
}

__global__ __launch_bounds__(256) void ln2_kernel(const float* __restrict__ skip,
                                                  const float* __restrict__ fcc,
                                                  const float* __restrict__ g,
                                                  const float* __restrict__ bt,
                                                  const float* __restrict__ x,
                                                  const float* __restrict__ alphap,
                                                  float* __restrict__ out) {
  const int row = blockIdx.x, tid = threadIdx.x;
  float4 sv = ((const float4*)(skip + row * 1024))[tid];
  float4 fv = ((const float4*)(fcc + row * 1024))[tid];
  float4 v = {sv.x + fv.x, sv.y + fv.y, sv.z + fv.z, sv.w + fv.w};
  float s = v.x + v.y + v.z + v.w;
  float sq = v.x * v.x + v.y * v.y + v.z * v.z + v.w * v.w;
#pragma unroll
  for (int off = 1; off < 64; off <<= 1) { s += __shfl_xor(s, off); sq += __shfl_xor(sq, off); }
  __shared__ float ws[8];
  int wv = tid >> 6, l = tid & 63;
  if (l == 0) { ws[wv] = s; ws[4 + wv] = sq; }
  __syncthreads();
  s = ws[0] + ws[1] + ws[2] + ws[3];
  sq = ws[4] + ws[5] + ws[6] + ws[7];
  float mean = s * (1.0f / 1024.0f);
  float var = sq * (1.0f / 1024.0f) - mean * mean;
  float rs = rsqrtf(var + 1e-5f);
  float4 gv = ((const float4*)g)[tid];
  float4 bv = ((const float4*)bt)[tid];
  float alpha = alphap[0];
  float beta = 1.0f - alpha;
  float4 xv = ((const float4*)(x + row * 1024))[tid];
  float4 y;
  y.x = xv.x * alpha + ((v.x - mean) * rs * gv.x + bv.x) * beta;
  y.y = xv.y * alpha + ((v.y - mean) * rs * gv.y + bv.y) * beta;
  y.z = xv.z * alpha + ((v.z - mean) * rs * gv.z + bv.z) * beta;
  y.w = xv.w * alpha + ((v.w - mean) * rs * gv.w + bv.w) * beta;
  ((float4*)(out + row * 1024))[tid] = y;
}

// ---------------- launch ----------------
extern "C" void kernel_launch(void* const* d_in, const int* in_sizes, int n_in,
                              void* d_out, int out_size, void* d_ws, size_t ws_size,
                              hipStream_t stream) {
  const float* x  = (const float*)d_in[0];
  const int* mask = (const int*)d_in[1];
  const float* Wq = (const float*)d_in[2];
  const float* bq = (const float*)d_in[3];
  const float* Wk = (const float*)d_in[4];
  const float* bk = (const float*)d_in[5];
  const float* Wv = (const float*)d_in[6];
  const float* bv = (const float*)d_in[7];
  const float* Wo = (const float*)d_in[8];
  const float* bo = (const float*)d_in[9];
  const float* g1 = (const float*)d_in[10];
  const float* b1 = (const float*)d_in[11];
  const float* Wf = (const float*)d_in[12];
  const float* bf = (const float*)d_in[13];
  const float* g2 = (const float*)d_in[14];
  const float* b2 = (const float*)d_in[15];
  const float* alpha = (const float*)d_in[16];
  float* out = (float*)d_out;

  char* ws = (char*)d_ws;
  size_t off = 0;
  unsigned short* xb   = (unsigned short*)(ws + off); off += 8388608;   // 4096x1024 bf16
  unsigned short* Wqkv = (unsigned short*)(ws + off); off += 6291456;   // 3072x1024 bf16
  unsigned short* Wob  = (unsigned short*)(ws + off); off += 2097152;
  unsigned short* Wfb  = (unsigned short*)(ws + off); off += 2097152;
  float* bcat          = (float*)(ws + off);          off += 12288;
  float* maf           = (float*)(ws + off);          off += 16384;     // maskadd [4][1024]
  float2* mlbuf        = (float2*)(ws + off);         off += 1048576;   // (m,l)[2][64][1024]
  unsigned short* qkvb = (unsigned short*)(ws + off); off += 25165824;  // 4096x3072 bf16
  unsigned short* attb = (unsigned short*)(ws + off); off += 8388608;
  float* tmp           = (float*)(ws + off);          off += 16777216;  // VT+Opart1 (attn) -> att@Wo -> fcc
  float* s1f           = (float*)(ws + off);          off += 16777216;
  unsigned short* s1b  = (unsigned short*)(ws + off); off += 8388608;

  unsigned short* VT = (unsigned short*)tmp;                    // 8MB, attn-phase only
  unsigned short* Opart0 = s1b;                                 // 8MB, attn-phase only
  unsigned short* Opart1 = (unsigned short*)(tmp + 2097152);    // tmp second 8MB

  // fused casts + prep
  cast_all<<<9216, 256, 0, stream>>>(x, Wq, Wk, Wv, Wo, Wf, xb, Wqkv, Wob, Wfb);
  maskadd_kernel<<<16, 256, 0, stream>>>(mask, maf);
  hipMemcpyAsync(bcat,        bq, 4096, hipMemcpyDeviceToDevice, stream);
  hipMemcpyAsync(bcat + 1024, bk, 4096, hipMemcpyDeviceToDevice, stream);
  hipMemcpyAsync(bcat + 2048, bv, 4096, hipMemcpyDeviceToDevice, stream);

  // fused QKV GEMM: [4096,1024] x [3072,1024]^T -> bf16 [4096,3072]
  gemm_lds<0><<<dim3(32, 24), 256, 0, stream>>>(xb, Wqkv, bcat, qkvb, 4096, 3072, 1024);

  // V transpose -> VT[(bh*64+d)][k]
  vtrans_kernel<<<dim3(64, 16), 256, 0, stream>>>(qkvb, VT);

  // attention, K-split x2 -> per-split normalized O + (m,l)
  attn7_kernel<<<dim3(64, 8, 2), 256, 0, stream>>>(qkvb, VT, maf, Opart0, Opart1, mlbuf);

  // combine splits -> att bf16 [4096,1024]
  combine_kernel<<<4096, 256, 0, stream>>>(Opart0, Opart1, mlbuf, attb);

  // O projection -> f32 tmp
  gemm_lds<1><<<dim3(32, 8), 256, 0, stream>>>(attb, Wob, bo, tmp, 4096, 1024, 1024);

  // LN1: skip1 = LN(x + tmp); emits f32 + bf16
  ln1_kernel<<<4096, 256, 0, stream>>>(x, tmp, g1, b1, s1f, s1b);

  // FF GEMM + exact GELU -> f32 (reuse tmp)
  gemm_lds<2><<<dim3(32, 8), 256, 0, stream>>>(s1b, Wfb, bf, tmp, 4096, 1024, 1024);

  // LN2 + final mix
  ln2_kernel<<<4096, 256, 0, stream>>>(s1f, tmp, g2, b2, x, alpha, out);
}

// Round 11
// 204.577 us; speedup vs baseline: 1.0586x; 1.0586x over previous
//
#include <hip/hip_runtime.h>
#include <hip/hip_bf16.h>
#include <string.h>

typedef __attribute__((ext_vector_type(8))) short short8;
typedef __attribute__((ext_vector_type(4))) float f32x4;
typedef __attribute__((ext_vector_type(4))) unsigned short u16x4;

#define MFMA_BF16(a, b, c) __builtin_amdgcn_mfma_f32_16x16x32_bf16((a), (b), (c), 0, 0, 0)

__device__ __forceinline__ unsigned short f2bf(float f) {
  unsigned int u = __builtin_bit_cast(unsigned int, f);
  u += 0x7fffu + ((u >> 16) & 1u);
  return (unsigned short)(u >> 16);
}

// pack 2 f32 -> 1 dword of 2 bf16 (RTNE) via compiler-emitted v_cvt_pk_bf16_f32
__device__ __forceinline__ unsigned pk_bf16(float a, float b) {
  __hip_bfloat162 h = __float22bfloat162_rn(float2{a, b});
  unsigned r;
  memcpy(&r, &h, 4);
  return r;
}

// async global->LDS, 16 bytes per lane; LDS dest = wave-uniform base + lane*16
__device__ __forceinline__ void gload_lds16(const void* g, void* lds) {
  __builtin_amdgcn_global_load_lds(
      (const __attribute__((address_space(1))) unsigned int*)g,
      (__attribute__((address_space(3))) unsigned int*)lds, 16, 0, 0);
}

// ---------------- fused cast f32 -> bf16 for x + 5 weight matrices ----------------
__global__ __launch_bounds__(256) void cast_all(const float* __restrict__ x,
                                                const float* __restrict__ Wq,
                                                const float* __restrict__ Wk,
                                                const float* __restrict__ Wv,
                                                const float* __restrict__ Wo,
                                                const float* __restrict__ Wf,
                                                unsigned short* __restrict__ xb,
                                                unsigned short* __restrict__ Wqkv,
                                                unsigned short* __restrict__ Wob,
                                                unsigned short* __restrict__ Wfb) {
  int i = blockIdx.x * 256 + threadIdx.x;
  const float* src;
  unsigned short* dst;
  int j;
  if (i < 1048576)      { src = x;  dst = xb;             j = i; }
  else if (i < 1310720) { src = Wq; dst = Wqkv;           j = i - 1048576; }
  else if (i < 1572864) { src = Wk; dst = Wqkv + 1048576; j = i - 1310720; }
  else if (i < 1835008) { src = Wv; dst = Wqkv + 2097152; j = i - 1572864; }
  else if (i < 2097152) { src = Wo; dst = Wob;            j = i - 1835008; }
  else                  { src = Wf; dst = Wfb;            j = i - 2097152; }
  float4 v = ((const float4*)src)[j];
  u16x4 r = { f2bf(v.x), f2bf(v.y), f2bf(v.z), f2bf(v.w) };
  ((u16x4*)dst)[j] = r;
}

// ---------------- prep: maskadd (log2 domain) + QKV bias concat ----------------
__global__ __launch_bounds__(256) void prep_kernel(const int* __restrict__ mask,
                                                   const float* __restrict__ bq,
                                                   const float* __restrict__ bk,
                                                   const float* __restrict__ bv,
                                                   float* __restrict__ ma,
                                                   float* __restrict__ bcat) {
  int i = blockIdx.x * 256 + threadIdx.x;
  if (i < 4096) ma[i] = (mask[i] == 0) ? -1.4426950408889634e10f : 0.0f;
  int j = i - 4096;
  if (j >= 0 && j < 3072) {
    float v = (j < 1024) ? bq[j] : (j < 2048 ? bk[j - 1024] : bv[j - 2048]);
    bcat[j] = v;
  }
}

// ---------------- GEMM (m97 structure): C[M,N] = A[M,K] * W[N,K]^T + bias ----------------
template <int EPI>
__global__ __launch_bounds__(256) void gemm_lds(const unsigned short* __restrict__ A,
                                                const unsigned short* __restrict__ W,
                                                const float* __restrict__ bias,
                                                void* __restrict__ Cout,
                                                int M, int N, int K) {
  __shared__ unsigned short At[128 * 32];
  __shared__ unsigned short Bt[128 * 32];

  const int tid = threadIdx.x;
  const int w = tid >> 6, l = tid & 63;
  const int lr = l & 15, lq = l >> 4;
  const int wr = w >> 1, wc = w & 1;
  const int row0 = blockIdx.x * 128;
  const int col0 = blockIdx.y * 128;

  const int srow = l >> 2;
  const int skoff = (l & 3) * 8;

  f32x4 acc[4][4] = {};

  const unsigned short* Abase = A + (row0 + srow) * (size_t)K + skoff;
  const unsigned short* Bbase = W + (col0 + srow) * (size_t)K + skoff;

  for (int kt = 0; kt < K; kt += 32) {
#pragma unroll
    for (int j = 0; j < 2; j++) {
      const int c = w * 2 + j;
      gload_lds16(Abase + (size_t)(c * 16) * K + kt, &At[c * 512]);
      gload_lds16(Bbase + (size_t)(c * 16) * K + kt, &Bt[c * 512]);
    }
    __syncthreads();

    short8 af[4], bfr[4];
#pragma unroll
    for (int m = 0; m < 4; m++)
      af[m] = *(const short8*)&At[(wr * 64 + m * 16 + lr) * 32 + lq * 8];
#pragma unroll
    for (int n = 0; n < 4; n++)
      bfr[n] = *(const short8*)&Bt[(wc * 64 + n * 16 + lr) * 32 + lq * 8];
#pragma unroll
    for (int m = 0; m < 4; m++)
#pragma unroll
      for (int n = 0; n < 4; n++)
        acc[m][n] = MFMA_BF16(af[m], bfr[n], acc[m][n]);
    __syncthreads();
  }

#pragma unroll
  for (int n = 0; n < 4; n++) {
    const int col = col0 + wc * 64 + n * 16 + lr;
    const float bv = bias[col];
#pragma unroll
    for (int m = 0; m < 4; m++) {
      const int row = row0 + wr * 64 + m * 16 + lq * 4;
#pragma unroll
      for (int r = 0; r < 4; r++) {
        float v = acc[m][n][r] + bv;
        if (EPI == 0) {
          ((unsigned short*)Cout)[(size_t)(row + r) * N + col] = f2bf(v);
        } else if (EPI == 1) {
          ((float*)Cout)[(size_t)(row + r) * N + col] = v;
        } else {
          float g = 0.5f * v * (1.0f + erff(v * 0.70710678118654752f));
          ((float*)Cout)[(size_t)(row + r) * N + col] = g;
        }
      }
    }
  }
}

// ---------------- V transpose: VT[(bh*64+d)][k] <- v-slab of qkv ----------------
__global__ __launch_bounds__(256) void vtrans_kernel(const unsigned short* __restrict__ qkv,
                                                     unsigned short* __restrict__ VT) {
  const int bh = blockIdx.x;   // 64
  const int kt = blockIdx.y;   // 16 tiles of 64 keys
  const int t = threadIdx.x;
  const int d = t & 63, kg = t >> 6;
  const unsigned short* basev =
      qkv + ((size_t)(bh >> 4) * 1024 + (bh & 15) * 64) * 3072 + 2048;
  const unsigned short* src = basev + (size_t)(kt * 4 + kg) * 3072 + d;
  unsigned short vals[16];
#pragma unroll
  for (int j = 0; j < 16; j++) vals[j] = src[j * 64];
  short8 v0, v1;
#pragma unroll
  for (int j = 0; j < 8; j++) { v0[j] = (short)vals[j]; v1[j] = (short)vals[8 + j]; }
  size_t dst = ((size_t)bh * 64 + d) * 1024 + kt * 64 + kg * 16;
  *(short8*)&VT[dst] = v0;
  *(short8*)&VT[dst + 8] = v1;
}

// ---------------- flash attention v8 ----------------
// attn6 structure + stable-skip rescale (exact), cvt_pk P-packing, s_setprio.
struct Frags {
  short8 kf[2][2];   // [key-half][d-chunk]
  short8 vf[4];      // V^T frags per d-tile
};

__device__ __forceinline__ void load_frags(Frags& f, int kt,
                                           const unsigned short* __restrict__ basek,
                                           const unsigned short* __restrict__ vtb,
                                           int lr, int lq) {
#pragma unroll
  for (int t = 0; t < 2; t++) {
    const unsigned short* ka = basek + (size_t)(kt * 2 + t) * 3072 + lr * 64;
    f.kf[t][0] = *(const short8*)(ka + lq * 8);
    f.kf[t][1] = *(const short8*)(ka + 32 + lq * 8);
  }
#pragma unroll
  for (int n = 0; n < 4; n++)
    f.vf[n] = *(const short8*)(vtb + (size_t)(n * 16 + lr) * 1024 + kt * 32 + lq * 8);
}

__device__ __forceinline__ void process(const Frags& f, int kcur, const short8 qf[2][2],
                                        const float* __restrict__ ma_lds,
                                        unsigned short* pw0, unsigned short* pw1,
                                        float m[2], float ll[2], f32x4 o[2][4],
                                        int lr, int lq) {
  constexpr float SC = 0.18033688011112042f;  // 0.125 * log2(e)
  unsigned short* pws[2] = {pw0, pw1};
  const float4 mk0 = *(const float4*)&ma_lds[kcur * 32 + lq * 4];
  const float4 mk1 = *(const float4*)&ma_lds[kcur * 32 + 16 + lq * 4];
#pragma unroll
  for (int qt2 = 0; qt2 < 2; qt2++) {
    // S^T tiles: rows = keys (lq*4+r [+16]), cols = q (lr)
    f32x4 s0 = {0.f, 0.f, 0.f, 0.f}, s1 = {0.f, 0.f, 0.f, 0.f};
    __builtin_amdgcn_s_setprio(1);
    s0 = MFMA_BF16(f.kf[0][0], qf[qt2][0], s0);
    s0 = MFMA_BF16(f.kf[0][1], qf[qt2][1], s0);
    s1 = MFMA_BF16(f.kf[1][0], qf[qt2][0], s1);
    s1 = MFMA_BF16(f.kf[1][1], qf[qt2][1], s1);
    __builtin_amdgcn_s_setprio(0);
    float sv[8];
#pragma unroll
    for (int r = 0; r < 4; r++) {
      sv[r]     = s0[r] * SC + ((const float*)&mk0)[r];
      sv[4 + r] = s1[r] * SC + ((const float*)&mk1)[r];
    }
    // online softmax (exp2 domain): state lane-local for q = lr; max over lq group
    float t = fmaxf(fmaxf(fmaxf(sv[0], sv[1]), fmaxf(sv[2], sv[3])),
                    fmaxf(fmaxf(sv[4], sv[5]), fmaxf(sv[6], sv[7])));
    t = fmaxf(t, __shfl_xor(t, 16));
    t = fmaxf(t, __shfl_xor(t, 32));
    const float mn = fmaxf(m[qt2], t);
    // stable-skip: if max didn't grow on any lane, rescale is *1.0 -> skip (exact)
    if (!__all(mn == m[qt2])) {
      const float sc = __builtin_amdgcn_exp2f(m[qt2] - mn);
      m[qt2] = mn;
      ll[qt2] *= sc;
      float scr[4];
#pragma unroll
      for (int r = 0; r < 4; r++) scr[r] = __shfl(sc, lq * 4 + r);
#pragma unroll
      for (int n = 0; n < 4; n++)
#pragma unroll
        for (int r = 0; r < 4; r++) o[qt2][n][r] *= scr[r];
    }
    float p[8], rs = 0.f;
#pragma unroll
    for (int i = 0; i < 8; i++) { p[i] = __builtin_amdgcn_exp2f(sv[i] - m[qt2]); rs += p[i]; }
    // deferred l-reduction: ll stays lane-partial (this lane's 8 keys)
    ll[qt2] += rs;
    // pack P (bf16) to per-wave LDS: P[q=lr][k_local], stride 40
    uint2 wa, wb;
    wa.x = pk_bf16(p[0], p[1]);
    wa.y = pk_bf16(p[2], p[3]);
    wb.x = pk_bf16(p[4], p[5]);
    wb.y = pk_bf16(p[6], p[7]);
    *(uint2*)&pws[qt2][lr * 40 + lq * 4] = wa;
    *(uint2*)&pws[qt2][lr * 40 + 16 + lq * 4] = wb;
  }
  asm volatile("s_waitcnt lgkmcnt(0)" ::: "memory");
  // PV: A = P[q=lr][k=lq*8..+7] (b128 from LDS), B = V^T frags
#pragma unroll
  for (int qt2 = 0; qt2 < 2; qt2++) {
    const short8 pa = *(const short8*)&pws[qt2][lr * 40 + lq * 8];
    __builtin_amdgcn_s_setprio(1);
#pragma unroll
    for (int n = 0; n < 4; n++)
      o[qt2][n] = MFMA_BF16(pa, f.vf[n], o[qt2][n]);
    __builtin_amdgcn_s_setprio(0);
  }
}

__global__ __launch_bounds__(256) void attn8_kernel(const unsigned short* __restrict__ qkv,
                                                    const unsigned short* __restrict__ VT,
                                                    const float* __restrict__ maskadd,
                                                    unsigned short* __restrict__ att) {
  __shared__ float ma_lds[1024];
  __shared__ unsigned short Pl[4][2][640];  // per wave, per q-tile: [16 q][40]

  const int bh = blockIdx.x, b = bh >> 4, h = bh & 15;
  const int qb = blockIdx.y;
  const int tid = threadIdx.x, w = tid >> 6, l = tid & 63;
  const int lr = l & 15, lq = l >> 4;

  const unsigned short* baseq = qkv + ((size_t)b * 1024 + h * 64) * 3072;
  const unsigned short* basek = baseq + 1024;
  const unsigned short* vtb = VT + (size_t)bh * 64 * 1024;

  // stage scaled mask row into LDS once
  ((float4*)ma_lds)[tid] = ((const float4*)(maskadd + b * 1024))[tid];
  __syncthreads();

  // Q fragments (2 tiles x 2 d-chunks), resident all kernel
  short8 qf[2][2];
  const int q0 = qb * 128 + w * 32;
#pragma unroll
  for (int t = 0; t < 2; t++) {
    int p = q0 + t * 16 + lr;
    const unsigned short* qa = baseq + (p >> 4) * 3072 + (p & 15) * 64;
    qf[t][0] = *(const short8*)(qa + lq * 8);
    qf[t][1] = *(const short8*)(qa + 32 + lq * 8);
  }

  float m[2] = {-1e30f, -1e30f}, ll[2] = {0.f, 0.f};
  f32x4 o[2][4] = {};

  unsigned short* pw0 = &Pl[w][0][0];
  unsigned short* pw1 = &Pl[w][1][0];

  Frags fa, fb;
  load_frags(fa, 0, basek, vtb, lr, lq);
#pragma unroll 1
  for (int kt = 0; kt < 32; kt += 2) {
    load_frags(fb, (kt + 1) & 31, basek, vtb, lr, lq);
    process(fa, kt, qf, ma_lds, pw0, pw1, m, ll, o, lr, lq);
    load_frags(fa, (kt + 2) & 31, basek, vtb, lr, lq);
    process(fb, kt + 1, qf, ma_lds, pw0, pw1, m, ll, o, lr, lq);
  }

  // epilogue: finish deferred l-reduction, normalize, write att[b, q, h*64 + d]
#pragma unroll
  for (int qt2 = 0; qt2 < 2; qt2++) {
    float lf = ll[qt2];
    lf += __shfl_xor(lf, 16);
    lf += __shfl_xor(lf, 32);
    float inv[4];
#pragma unroll
    for (int r = 0; r < 4; r++) inv[r] = 1.0f / __shfl(lf, lq * 4 + r);
#pragma unroll
    for (int r = 0; r < 4; r++) {
      int q = q0 + qt2 * 16 + lq * 4 + r;
      size_t obase = ((size_t)b * 1024 + q) * 1024 + h * 64;
#pragma unroll
      for (int n = 0; n < 4; n++)
        att[obase + n * 16 + lr] = f2bf(o[qt2][n][r] * inv[r]);
    }
  }
}

// ---------------- LayerNorm kernels (fp32, E=1024, one row per block) ----------------
__global__ __launch_bounds__(256) void ln1_kernel(const float* __restrict__ x,
                                                  const float* __restrict__ attp,
                                                  const float* __restrict__ g,
                                                  const float* __restrict__ bt,
                                                  float* __restrict__ sf,
                                                  unsigned short* __restrict__ sb) {
  const int row = blockIdx.x, tid = threadIdx.x;
  float4 xv = ((const float4*)(x + row * 1024))[tid];
  float4 av = ((const float4*)(attp + row * 1024))[tid];
  float4 v = {xv.x + av.x, xv.y + av.y, xv.z + av.z, xv.w + av.w};
  float s = v.x + v.y + v.z + v.w;
  float sq = v.x * v.x + v.y * v.y + v.z * v.z + v.w * v.w;
#pragma unroll
  for (int off = 1; off < 64; off <<= 1) { s += __shfl_xor(s, off); sq += __shfl_xor(sq, off); }
  __shared__ float ws[8];
  int wv = tid >> 6, l = tid & 63;
  if (l == 0) { ws[wv] = s; ws[4 + wv] = sq; }
  __syncthreads();
  s = ws[0] + ws[1] + ws[2] + ws[3];
  sq = ws[4] + ws[5] + ws[6] + ws[7];
  float mean = s * (1.0f / 1024.0f);
  float var = sq * (1.0f / 1024.0f) - mean * mean;
  float rs = rsqrtf(var + 1e-5f);
  float4 gv = ((const float4*)g)[tid];
  float4 bv = ((const float4*)bt)[tid];
  float4 y;
  y.x = (v.x - mean) * rs * gv.x + bv.x;
  y.y = (v.y - mean) * rs * gv.y + bv.y;
  y.z = (v.z - mean) * rs * gv.z + bv.z;
  y.w = (v.w - mean) * rs * gv.w + bv.w;
  ((float4*)(sf + row * 1024))[tid] = y;
  u16x4 yb = { f2bf(y.x), f2bf(y.y), f2bf(y.z), f2bf(y.w) };
  ((u16x4*)(sb + row * 1024))[tid] = yb;
}

__global__ __launch_bounds__(256) void ln2_kernel(const float* __restrict__ skip,
                                                  const float* __restrict__ fcc,
                                                  const float* __restrict__ g,
                                                  const float* __restrict__ bt,
                                                  const float* __restrict__ x,
                                                  const float* __restrict__ alphap,
                                                  float* __restrict__ out) {
  const int row = blockIdx.x, tid = threadIdx.x;
  float4 sv = ((const float4*)(skip + row * 1024))[tid];
  float4 fv = ((const float4*)(fcc + row * 1024))[tid];
  float4 v = {sv.x + fv.x, sv.y + fv.y, sv.z + fv.z, sv.w + fv.w};
  float s = v.x + v.y + v.z + v.w;
  float sq = v.x * v.x + v.y * v.y + v.z * v.z + v.w * v.w;
#pragma unroll
  for (int off = 1; off < 64; off <<= 1) { s += __shfl_xor(s, off); sq += __shfl_xor(sq, off); }
  __shared__ float ws[8];
  int wv = tid >> 6, l = tid & 63;
  if (l == 0) { ws[wv] = s; ws[4 + wv] = sq; }
  __syncthreads();
  s = ws[0] + ws[1] + ws[2] + ws[3];
  sq = ws[4] + ws[5] + ws[6] + ws[7];
  float mean = s * (1.0f / 1024.0f);
  float var = sq * (1.0f / 1024.0f) - mean * mean;
  float rs = rsqrtf(var + 1e-5f);
  float4 gv = ((const float4*)g)[tid];
  float4 bv = ((const float4*)bt)[tid];
  float alpha = alphap[0];
  float beta = 1.0f - alpha;
  float4 xv = ((const float4*)(x + row * 1024))[tid];
  float4 y;
  y.x = xv.x * alpha + ((v.x - mean) * rs * gv.x + bv.x) * beta;
  y.y = xv.y * alpha + ((v.y - mean) * rs * gv.y + bv.y) * beta;
  y.z = xv.z * alpha + ((v.z - mean) * rs * gv.z + bv.z) * beta;
  y.w = xv.w * alpha + ((v.w - mean) * rs * gv.w + bv.w) * beta;
  ((float4*)(out + row * 1024))[tid] = y;
}

// ---------------- launch ----------------
extern "C" void kernel_launch(void* const* d_in, const int* in_sizes, int n_in,
                              void* d_out, int out_size, void* d_ws, size_t ws_size,
                              hipStream_t stream) {
  const float* x  = (const float*)d_in[0];
  const int* mask = (const int*)d_in[1];
  const float* Wq = (const float*)d_in[2];
  const float* bq = (const float*)d_in[3];
  const float* Wk = (const float*)d_in[4];
  const float* bk = (const float*)d_in[5];
  const float* Wv = (const float*)d_in[6];
  const float* bv = (const float*)d_in[7];
  const float* Wo = (const float*)d_in[8];
  const float* bo = (const float*)d_in[9];
  const float* g1 = (const float*)d_in[10];
  const float* b1 = (const float*)d_in[11];
  const float* Wf = (const float*)d_in[12];
  const float* bf = (const float*)d_in[13];
  const float* g2 = (const float*)d_in[14];
  const float* b2 = (const float*)d_in[15];
  const float* alpha = (const float*)d_in[16];
  float* out = (float*)d_out;

  char* ws = (char*)d_ws;
  size_t off = 0;
  unsigned short* xb   = (unsigned short*)(ws + off); off += 8388608;   // 4096x1024 bf16
  unsigned short* Wqkv = (unsigned short*)(ws + off); off += 6291456;   // 3072x1024 bf16
  unsigned short* Wob  = (unsigned short*)(ws + off); off += 2097152;
  unsigned short* Wfb  = (unsigned short*)(ws + off); off += 2097152;
  float* bcat          = (float*)(ws + off);          off += 12288;
  float* maf           = (float*)(ws + off);          off += 16384;     // maskadd [4][1024]
  unsigned short* qkvb = (unsigned short*)(ws + off); off += 25165824;  // 4096x3072 bf16
  unsigned short* attb = (unsigned short*)(ws + off); off += 8388608;
  float* tmp           = (float*)(ws + off);          off += 16777216;  // VT (attn) -> att@Wo -> fcc
  float* s1f           = (float*)(ws + off);          off += 16777216;
  unsigned short* s1b  = (unsigned short*)(ws + off); off += 8388608;

  unsigned short* VT = (unsigned short*)tmp;  // 8MB, used only during attention

  // fused casts + prep (maskadd + bias concat)
  cast_all<<<9216, 256, 0, stream>>>(x, Wq, Wk, Wv, Wo, Wf, xb, Wqkv, Wob, Wfb);
  prep_kernel<<<28, 256, 0, stream>>>(mask, bq, bk, bv, maf, bcat);

  // fused QKV GEMM: [4096,1024] x [3072,1024]^T -> bf16 [4096,3072]
  gemm_lds<0><<<dim3(32, 24), 256, 0, stream>>>(xb, Wqkv, bcat, qkvb, 4096, 3072, 1024);

  // V transpose -> VT[(bh*64+d)][k]
  vtrans_kernel<<<dim3(64, 16), 256, 0, stream>>>(qkvb, VT);

  // attention -> att bf16 [4096,1024]
  attn8_kernel<<<dim3(64, 8), 256, 0, stream>>>(qkvb, VT, maf, attb);

  // O projection -> f32 tmp
  gemm_lds<1><<<dim3(32, 8), 256, 0, stream>>>(attb, Wob, bo, tmp, 4096, 1024, 1024);

  // LN1: skip1 = LN(x + tmp); emits f32 + bf16
  ln1_kernel<<<4096, 256, 0, stream>>>(x, tmp, g1, b1, s1f, s1b);

  // FF GEMM + exact GELU -> f32 (reuse tmp)
  gemm_lds<2><<<dim3(32, 8), 256, 0, stream>>>(s1b, Wfb, bf, tmp, 4096, 1024, 1024);

  // LN2 + final mix
  ln2_kernel<<<4096, 256, 0, stream>>>(s1f, tmp, g2, b2, x, alpha, out);
}

// Round 12
// 191.177 us; speedup vs baseline: 1.1328x; 1.0701x over previous
//
#include <hip/hip_runtime.h>
#include <hip/hip_bf16.h>
#include <string.h>

typedef __attribute__((ext_vector_type(8))) short short8;
typedef __attribute__((ext_vector_type(4))) float f32x4;
typedef __attribute__((ext_vector_type(4))) unsigned short u16x4;

#define MFMA_BF16(a, b, c) __builtin_amdgcn_mfma_f32_16x16x32_bf16((a), (b), (c), 0, 0, 0)

__device__ __forceinline__ unsigned short f2bf(float f) {
  unsigned int u = __builtin_bit_cast(unsigned int, f);
  u += 0x7fffu + ((u >> 16) & 1u);
  return (unsigned short)(u >> 16);
}

// pack 2 f32 -> 1 dword of 2 bf16 (RTNE) via compiler-emitted v_cvt_pk_bf16_f32
__device__ __forceinline__ unsigned pk_bf16(float a, float b) {
  __hip_bfloat162 h = __float22bfloat162_rn(float2{a, b});
  unsigned r;
  memcpy(&r, &h, 4);
  return r;
}

// async global->LDS, 16 bytes per lane; LDS dest = wave-uniform base + lane*16
__device__ __forceinline__ void gload_lds16(const void* g, void* lds) {
  __builtin_amdgcn_global_load_lds(
      (const __attribute__((address_space(1))) unsigned int*)g,
      (__attribute__((address_space(3))) unsigned int*)lds, 16, 0, 0);
}

// ---------------- fused cast f32 -> bf16 for x + 5 weight matrices ----------------
__global__ __launch_bounds__(256) void cast_all(const float* __restrict__ x,
                                                const float* __restrict__ Wq,
                                                const float* __restrict__ Wk,
                                                const float* __restrict__ Wv,
                                                const float* __restrict__ Wo,
                                                const float* __restrict__ Wf,
                                                unsigned short* __restrict__ xb,
                                                unsigned short* __restrict__ Wqkv,
                                                unsigned short* __restrict__ Wob,
                                                unsigned short* __restrict__ Wfb) {
  int i = blockIdx.x * 256 + threadIdx.x;
  const float* src;
  unsigned short* dst;
  int j;
  if (i < 1048576)      { src = x;  dst = xb;             j = i; }
  else if (i < 1310720) { src = Wq; dst = Wqkv;           j = i - 1048576; }
  else if (i < 1572864) { src = Wk; dst = Wqkv + 1048576; j = i - 1310720; }
  else if (i < 1835008) { src = Wv; dst = Wqkv + 2097152; j = i - 1572864; }
  else if (i < 2097152) { src = Wo; dst = Wob;            j = i - 1835008; }
  else                  { src = Wf; dst = Wfb;            j = i - 2097152; }
  float4 v = ((const float4*)src)[j];
  u16x4 r = { f2bf(v.x), f2bf(v.y), f2bf(v.z), f2bf(v.w) };
  ((u16x4*)dst)[j] = r;
}

// ---------------- prep: maskadd (log2 domain) + QKV bias concat ----------------
__global__ __launch_bounds__(256) void prep_kernel(const int* __restrict__ mask,
                                                   const float* __restrict__ bq,
                                                   const float* __restrict__ bk,
                                                   const float* __restrict__ bv,
                                                   float* __restrict__ ma,
                                                   float* __restrict__ bcat) {
  int i = blockIdx.x * 256 + threadIdx.x;
  if (i < 4096) ma[i] = (mask[i] == 0) ? -1.4426950408889634e10f : 0.0f;
  int j = i - 4096;
  if (j >= 0 && j < 3072) {
    float v = (j < 1024) ? bq[j] : (j < 2048 ? bk[j - 1024] : bv[j - 2048]);
    bcat[j] = v;
  }
}

// ---------------- GEMM (m97 structure): C[M,N] = A[M,K] * W[N,K]^T + bias ----------------
template <int EPI>
__global__ __launch_bounds__(256) void gemm_lds(const unsigned short* __restrict__ A,
                                                const unsigned short* __restrict__ W,
                                                const float* __restrict__ bias,
                                                void* __restrict__ Cout,
                                                int M, int N, int K) {
  __shared__ unsigned short At[128 * 32];
  __shared__ unsigned short Bt[128 * 32];

  const int tid = threadIdx.x;
  const int w = tid >> 6, l = tid & 63;
  const int lr = l & 15, lq = l >> 4;
  const int wr = w >> 1, wc = w & 1;
  const int row0 = blockIdx.x * 128;
  const int col0 = blockIdx.y * 128;

  const int srow = l >> 2;
  const int skoff = (l & 3) * 8;

  f32x4 acc[4][4] = {};

  const unsigned short* Abase = A + (row0 + srow) * (size_t)K + skoff;
  const unsigned short* Bbase = W + (col0 + srow) * (size_t)K + skoff;

  for (int kt = 0; kt < K; kt += 32) {
#pragma unroll
    for (int j = 0; j < 2; j++) {
      const int c = w * 2 + j;
      gload_lds16(Abase + (size_t)(c * 16) * K + kt, &At[c * 512]);
      gload_lds16(Bbase + (size_t)(c * 16) * K + kt, &Bt[c * 512]);
    }
    __syncthreads();

    short8 af[4], bfr[4];
#pragma unroll
    for (int m = 0; m < 4; m++)
      af[m] = *(const short8*)&At[(wr * 64 + m * 16 + lr) * 32 + lq * 8];
#pragma unroll
    for (int n = 0; n < 4; n++)
      bfr[n] = *(const short8*)&Bt[(wc * 64 + n * 16 + lr) * 32 + lq * 8];
#pragma unroll
    for (int m = 0; m < 4; m++)
#pragma unroll
      for (int n = 0; n < 4; n++)
        acc[m][n] = MFMA_BF16(af[m], bfr[n], acc[m][n]);
    __syncthreads();
  }

#pragma unroll
  for (int n = 0; n < 4; n++) {
    const int col = col0 + wc * 64 + n * 16 + lr;
    const float bv = bias[col];
#pragma unroll
    for (int m = 0; m < 4; m++) {
      const int row = row0 + wr * 64 + m * 16 + lq * 4;
#pragma unroll
      for (int r = 0; r < 4; r++) {
        float v = acc[m][n][r] + bv;
        if (EPI == 0) {
          ((unsigned short*)Cout)[(size_t)(row + r) * N + col] = f2bf(v);
        } else if (EPI == 1) {
          ((float*)Cout)[(size_t)(row + r) * N + col] = v;
        } else {
          float g = 0.5f * v * (1.0f + erff(v * 0.70710678118654752f));
          ((float*)Cout)[(size_t)(row + r) * N + col] = g;
        }
      }
    }
  }
}

// ---------------- V transpose: VT[(bh*64+d)][k] <- v-slab of qkv ----------------
__global__ __launch_bounds__(256) void vtrans_kernel(const unsigned short* __restrict__ qkv,
                                                     unsigned short* __restrict__ VT) {
  const int bh = blockIdx.x;   // 64
  const int kt = blockIdx.y;   // 16 tiles of 64 keys
  const int t = threadIdx.x;
  const int d = t & 63, kg = t >> 6;
  const unsigned short* basev =
      qkv + ((size_t)(bh >> 4) * 1024 + (bh & 15) * 64) * 3072 + 2048;
  const unsigned short* src = basev + (size_t)(kt * 4 + kg) * 3072 + d;
  unsigned short vals[16];
#pragma unroll
  for (int j = 0; j < 16; j++) vals[j] = src[j * 64];
  short8 v0, v1;
#pragma unroll
  for (int j = 0; j < 8; j++) { v0[j] = (short)vals[j]; v1[j] = (short)vals[8 + j]; }
  size_t dst = ((size_t)bh * 64 + d) * 1024 + kt * 64 + kg * 16;
  *(short8*)&VT[dst] = v0;
  *(short8*)&VT[dst + 8] = v1;
}

// ---------------- flash attention v9: shared LDS K/V staging (m97-style) ----------------
// 4 waves share double-buffered K/V tiles staged via global_load_lds (1 barrier/tile).
// Per-wave math identical to attn8: swapped QK^T, exp2 softmax, stable-skip rescale,
// deferred l-reduction, pk_bf16 P-packing, s_setprio on MFMA clusters.
__global__ __launch_bounds__(256) void attn9_kernel(const unsigned short* __restrict__ qkv,
                                                    const unsigned short* __restrict__ VT,
                                                    const float* __restrict__ maskadd,
                                                    unsigned short* __restrict__ att) {
  __shared__ unsigned short Kt[2][2048];  // [buf][half c][32 key][32 shorts] (d = c*32+..)
  __shared__ unsigned short Vt[2][2048];  // [buf][64 d][32 k-shorts]
  __shared__ float ma_lds[1024];
  __shared__ unsigned short Pl[4][2][640];  // per wave, per q-tile: [16 q][40]

  const int bh = blockIdx.x, b = bh >> 4, h = bh & 15;
  const int qb = blockIdx.y;
  const int tid = threadIdx.x, w = tid >> 6, l = tid & 63;
  const int lr = l & 15, lq = l >> 4;

  const unsigned short* baseq = qkv + ((size_t)b * 1024 + h * 64) * 3072;
  const unsigned short* basek = baseq + 1024;
  const unsigned short* vtb = VT + (size_t)bh * 64 * 1024;

  // staging roles (per thread)
  const int skey = (tid >> 2) & 31;                 // K: key within tile
  const int skd = (tid >> 7) * 32 + (tid & 3) * 8;  // K: d offset (half + chunk)
  const int svd = tid >> 2;                         // V: d row
  const int svc = (tid & 3) * 8;                    // V: k chunk

  // stage scaled mask row + tile 0 of K/V
  ((float4*)ma_lds)[tid] = ((const float4*)(maskadd + b * 1024))[tid];
  {
    const int pk = skey;
    gload_lds16(basek + (pk >> 4) * 3072 + (pk & 15) * 64 + skd, (char*)&Kt[0][0] + w * 1024);
    gload_lds16(vtb + (size_t)svd * 1024 + svc, (char*)&Vt[0][0] + w * 1024);
  }

  // Q fragments (2 tiles x 2 d-chunks), resident all kernel
  short8 qf[2][2];
  const int q0 = qb * 128 + w * 32;
#pragma unroll
  for (int t = 0; t < 2; t++) {
    int p = q0 + t * 16 + lr;
    const unsigned short* qa = baseq + (p >> 4) * 3072 + (p & 15) * 64;
    qf[t][0] = *(const short8*)(qa + lq * 8);
    qf[t][1] = *(const short8*)(qa + 32 + lq * 8);
  }
  __syncthreads();  // drains vmcnt: tile 0 staged; mask visible

  float m[2] = {-1e30f, -1e30f}, ll[2] = {0.f, 0.f};
  f32x4 o[2][4] = {};
  unsigned short* pw0 = &Pl[w][0][0];
  unsigned short* pw1 = &Pl[w][1][0];
  unsigned short* pws[2] = {pw0, pw1};
  constexpr float SC = 0.18033688011112042f;  // 0.125 * log2(e)

  int buf = 0;
#pragma unroll 1
  for (int kt = 0; kt < 32; kt++) {
    // issue next tile's staging into the other buffer (async, drained at the barrier)
    if (kt < 31) {
      const int pk = (kt + 1) * 32 + skey;
      gload_lds16(basek + (pk >> 4) * 3072 + (pk & 15) * 64 + skd,
                  (char*)&Kt[buf ^ 1][0] + w * 1024);
      gload_lds16(vtb + (size_t)svd * 1024 + (kt + 1) * 32 + svc,
                  (char*)&Vt[buf ^ 1][0] + w * 1024);
    }

    // ---- process tile kt from LDS ----
    const unsigned short* KtL = &Kt[buf][0];
    const unsigned short* VtL = &Vt[buf][0];
    short8 vf[4];
#pragma unroll
    for (int n = 0; n < 4; n++)
      vf[n] = *(const short8*)&VtL[(n * 16 + lr) * 32 + lq * 8];

    const float4 mk0 = *(const float4*)&ma_lds[kt * 32 + lq * 4];
    const float4 mk1 = *(const float4*)&ma_lds[kt * 32 + 16 + lq * 4];
#pragma unroll
    for (int qt2 = 0; qt2 < 2; qt2++) {
      short8 kf00 = *(const short8*)&KtL[lr * 32 + lq * 8];
      short8 kf01 = *(const short8*)&KtL[1024 + lr * 32 + lq * 8];
      short8 kf10 = *(const short8*)&KtL[(16 + lr) * 32 + lq * 8];
      short8 kf11 = *(const short8*)&KtL[1024 + (16 + lr) * 32 + lq * 8];
      f32x4 s0 = {0.f, 0.f, 0.f, 0.f}, s1 = {0.f, 0.f, 0.f, 0.f};
      __builtin_amdgcn_s_setprio(1);
      s0 = MFMA_BF16(kf00, qf[qt2][0], s0);
      s0 = MFMA_BF16(kf01, qf[qt2][1], s0);
      s1 = MFMA_BF16(kf10, qf[qt2][0], s1);
      s1 = MFMA_BF16(kf11, qf[qt2][1], s1);
      __builtin_amdgcn_s_setprio(0);
      float sv[8];
#pragma unroll
      for (int r = 0; r < 4; r++) {
        sv[r]     = s0[r] * SC + ((const float*)&mk0)[r];
        sv[4 + r] = s1[r] * SC + ((const float*)&mk1)[r];
      }
      float t = fmaxf(fmaxf(fmaxf(sv[0], sv[1]), fmaxf(sv[2], sv[3])),
                      fmaxf(fmaxf(sv[4], sv[5]), fmaxf(sv[6], sv[7])));
      t = fmaxf(t, __shfl_xor(t, 16));
      t = fmaxf(t, __shfl_xor(t, 32));
      const float mn = fmaxf(m[qt2], t);
      if (!__all(mn == m[qt2])) {  // stable-skip (exact)
        const float sc = __builtin_amdgcn_exp2f(m[qt2] - mn);
        m[qt2] = mn;
        ll[qt2] *= sc;
        float scr[4];
#pragma unroll
        for (int r = 0; r < 4; r++) scr[r] = __shfl(sc, lq * 4 + r);
#pragma unroll
        for (int n = 0; n < 4; n++)
#pragma unroll
          for (int r = 0; r < 4; r++) o[qt2][n][r] *= scr[r];
      }
      float p[8], rs = 0.f;
#pragma unroll
      for (int i = 0; i < 8; i++) { p[i] = __builtin_amdgcn_exp2f(sv[i] - m[qt2]); rs += p[i]; }
      ll[qt2] += rs;  // deferred l-reduction (lane-partial)
      uint2 wa, wb;
      wa.x = pk_bf16(p[0], p[1]);
      wa.y = pk_bf16(p[2], p[3]);
      wb.x = pk_bf16(p[4], p[5]);
      wb.y = pk_bf16(p[6], p[7]);
      *(uint2*)&pws[qt2][lr * 40 + lq * 4] = wa;
      *(uint2*)&pws[qt2][lr * 40 + 16 + lq * 4] = wb;
    }
    asm volatile("s_waitcnt lgkmcnt(0)" ::: "memory");
#pragma unroll
    for (int qt2 = 0; qt2 < 2; qt2++) {
      const short8 pa = *(const short8*)&pws[qt2][lr * 40 + lq * 8];
      __builtin_amdgcn_s_setprio(1);
#pragma unroll
      for (int n = 0; n < 4; n++)
        o[qt2][n] = MFMA_BF16(pa, vf[n], o[qt2][n]);
      __builtin_amdgcn_s_setprio(0);
    }

    __syncthreads();  // readers done with buf; staged buf^1 drained (vmcnt)
    buf ^= 1;
  }

  // epilogue: finish deferred l-reduction, normalize, write att[b, q, h*64 + d]
#pragma unroll
  for (int qt2 = 0; qt2 < 2; qt2++) {
    float lf = ll[qt2];
    lf += __shfl_xor(lf, 16);
    lf += __shfl_xor(lf, 32);
    float inv[4];
#pragma unroll
    for (int r = 0; r < 4; r++) inv[r] = 1.0f / __shfl(lf, lq * 4 + r);
#pragma unroll
    for (int r = 0; r < 4; r++) {
      int q = q0 + qt2 * 16 + lq * 4 + r;
      size_t obase = ((size_t)b * 1024 + q) * 1024 + h * 64;
#pragma unroll
      for (int n = 0; n < 4; n++)
        att[obase + n * 16 + lr] = f2bf(o[qt2][n][r] * inv[r]);
    }
  }
}

// ---------------- LayerNorm kernels (fp32, E=1024, one row per block) ----------------
__global__ __launch_bounds__(256) void ln1_kernel(const float* __restrict__ x,
                                                  const float* __restrict__ attp,
                                                  const float* __restrict__ g,
                                                  const float* __restrict__ bt,
                                                  float* __restrict__ sf,
                                                  unsigned short* __restrict__ sb) {
  const int row = blockIdx.x, tid = threadIdx.x;
  float4 xv = ((const float4*)(x + row * 1024))[tid];
  float4 av = ((const float4*)(attp + row * 1024))[tid];
  float4 v = {xv.x + av.x, xv.y + av.y, xv.z + av.z, xv.w + av.w};
  float s = v.x + v.y + v.z + v.w;
  float sq = v.x * v.x + v.y * v.y + v.z * v.z + v.w * v.w;
#pragma unroll
  for (int off = 1; off < 64; off <<= 1) { s += __shfl_xor(s, off); sq += __shfl_xor(sq, off); }
  __shared__ float ws[8];
  int wv = tid >> 6, l = tid & 63;
  if (l == 0) { ws[wv] = s; ws[4 + wv] = sq; }
  __syncthreads();
  s = ws[0] + ws[1] + ws[2] + ws[3];
  sq = ws[4] + ws[5] + ws[6] + ws[7];
  float mean = s * (1.0f / 1024.0f);
  float var = sq * (1.0f / 1024.0f) - mean * mean;
  float rs = rsqrtf(var + 1e-5f);
  float4 gv = ((const float4*)g)[tid];
  float4 bv = ((const float4*)bt)[tid];
  float4 y;
  y.x = (v.x - mean) * rs * gv.x + bv.x;
  y.y = (v.y - mean) * rs * gv.y + bv.y;
  y.z = (v.z - mean) * rs * gv.z + bv.z;
  y.w = (v.w - mean) * rs * gv.w + bv.w;
  ((float4*)(sf + row * 1024))[tid] = y;
  u16x4 yb = { f2bf(y.x), f2bf(y.y), f2bf(y.z), f2bf(y.w) };
  ((u16x4*)(sb + row * 1024))[tid] = yb;
}

__global__ __launch_bounds__(256) void ln2_kernel(const float* __restrict__ skip,
                                                  const float* __restrict__ fcc,
                                                  const float* __restrict__ g,
                                                  const float* __restrict__ bt,
                                                  const float* __restrict__ x,
                                                  const float* __restrict__ alphap,
                                                  float* __restrict__ out) {
  const int row = blockIdx.x, tid = threadIdx.x;
  float4 sv = ((const float4*)(skip + row * 1024))[tid];
  float4 fv = ((const float4*)(fcc + row * 1024))[tid];
  float4 v = {sv.x + fv.x, sv.y + fv.y, sv.z + fv.z, sv.w + fv.w};
  float s = v.x + v.y + v.z + v.w;
  float sq = v.x * v.x + v.y * v.y + v.z * v.z + v.w * v.w;
#pragma unroll
  for (int off = 1; off < 64; off <<= 1) { s += __shfl_xor(s, off); sq += __shfl_xor(sq, off); }
  __shared__ float ws[8];
  int wv = tid >> 6, l = tid & 63;
  if (l == 0) { ws[wv] = s; ws[4 + wv] = sq; }
  __syncthreads();
  s = ws[0] + ws[1] + ws[2] + ws[3];
  sq = ws[4] + ws[5] + ws[6] + ws[7];
  float mean = s * (1.0f / 1024.0f);
  float var = sq * (1.0f / 1024.0f) - mean * mean;
  float rs = rsqrtf(var + 1e-5f);
  float4 gv = ((const float4*)g)[tid];
  float4 bv = ((const float4*)bt)[tid];
  float alpha = alphap[0];
  float beta = 1.0f - alpha;
  float4 xv = ((const float4*)(x + row * 1024))[tid];
  float4 y;
  y.x = xv.x * alpha + ((v.x - mean) * rs * gv.x + bv.x) * beta;
  y.y = xv.y * alpha + ((v.y - mean) * rs * gv.y + bv.y) * beta;
  y.z = xv.z * alpha + ((v.z - mean) * rs * gv.z + bv.z) * beta;
  y.w = xv.w * alpha + ((v.w - mean) * rs * gv.w + bv.w) * beta;
  ((float4*)(out + row * 1024))[tid] = y;
}

// ---------------- launch ----------------
extern "C" void kernel_launch(void* const* d_in, const int* in_sizes, int n_in,
                              void* d_out, int out_size, void* d_ws, size_t ws_size,
                              hipStream_t stream) {
  const float* x  = (const float*)d_in[0];
  const int* mask = (const int*)d_in[1];
  const float* Wq = (const float*)d_in[2];
  const float* bq = (const float*)d_in[3];
  const float* Wk = (const float*)d_in[4];
  const float* bk = (const float*)d_in[5];
  const float* Wv = (const float*)d_in[6];
  const float* bv = (const float*)d_in[7];
  const float* Wo = (const float*)d_in[8];
  const float* bo = (const float*)d_in[9];
  const float* g1 = (const float*)d_in[10];
  const float* b1 = (const float*)d_in[11];
  const float* Wf = (const float*)d_in[12];
  const float* bf = (const float*)d_in[13];
  const float* g2 = (const float*)d_in[14];
  const float* b2 = (const float*)d_in[15];
  const float* alpha = (const float*)d_in[16];
  float* out = (float*)d_out;

  char* ws = (char*)d_ws;
  size_t off = 0;
  unsigned short* xb   = (unsigned short*)(ws + off); off += 8388608;   // 4096x1024 bf16
  unsigned short* Wqkv = (unsigned short*)(ws + off); off += 6291456;   // 3072x1024 bf16
  unsigned short* Wob  = (unsigned short*)(ws + off); off += 2097152;
  unsigned short* Wfb  = (unsigned short*)(ws + off); off += 2097152;
  float* bcat          = (float*)(ws + off);          off += 12288;
  float* maf           = (float*)(ws + off);          off += 16384;     // maskadd [4][1024]
  unsigned short* qkvb = (unsigned short*)(ws + off); off += 25165824;  // 4096x3072 bf16
  unsigned short* attb = (unsigned short*)(ws + off); off += 8388608;
  float* tmp           = (float*)(ws + off);          off += 16777216;  // VT (attn) -> att@Wo -> fcc
  float* s1f           = (float*)(ws + off);          off += 16777216;
  unsigned short* s1b  = (unsigned short*)(ws + off); off += 8388608;

  unsigned short* VT = (unsigned short*)tmp;  // 8MB, used only during attention

  // fused casts + prep (maskadd + bias concat)
  cast_all<<<9216, 256, 0, stream>>>(x, Wq, Wk, Wv, Wo, Wf, xb, Wqkv, Wob, Wfb);
  prep_kernel<<<28, 256, 0, stream>>>(mask, bq, bk, bv, maf, bcat);

  // fused QKV GEMM: [4096,1024] x [3072,1024]^T -> bf16 [4096,3072]
  gemm_lds<0><<<dim3(32, 24), 256, 0, stream>>>(xb, Wqkv, bcat, qkvb, 4096, 3072, 1024);

  // V transpose -> VT[(bh*64+d)][k]
  vtrans_kernel<<<dim3(64, 16), 256, 0, stream>>>(qkvb, VT);

  // attention -> att bf16 [4096,1024]
  attn9_kernel<<<dim3(64, 8), 256, 0, stream>>>(qkvb, VT, maf, attb);

  // O projection -> f32 tmp
  gemm_lds<1><<<dim3(32, 8), 256, 0, stream>>>(attb, Wob, bo, tmp, 4096, 1024, 1024);

  // LN1: skip1 = LN(x + tmp); emits f32 + bf16
  ln1_kernel<<<4096, 256, 0, stream>>>(x, tmp, g1, b1, s1f, s1b);

  // FF GEMM + exact GELU -> f32 (reuse tmp)
  gemm_lds<2><<<dim3(32, 8), 256, 0, stream>>>(s1b, Wfb, bf, tmp, 4096, 1024, 1024);

  // LN2 + final mix
  ln2_kernel<<<4096, 256, 0, stream>>>(s1f, tmp, g2, b2, x, alpha, out);
}

// Round 13
// 187.471 us; speedup vs baseline: 1.1552x; 1.0198x over previous
//
#include <hip/hip_runtime.h>
#include <hip/hip_bf16.h>
#include <string.h>

typedef __attribute__((ext_vector_type(8))) short short8;
typedef __attribute__((ext_vector_type(4))) float f32x4;
typedef __attribute__((ext_vector_type(4))) unsigned short u16x4;

#define MFMA_BF16(a, b, c) __builtin_amdgcn_mfma_f32_16x16x32_bf16((a), (b), (c), 0, 0, 0)

__device__ __forceinline__ unsigned short f2bf(float f) {
  unsigned int u = __builtin_bit_cast(unsigned int, f);
  u += 0x7fffu + ((u >> 16) & 1u);
  return (unsigned short)(u >> 16);
}

// pack 2 f32 -> 1 dword of 2 bf16 (RTNE) via compiler-emitted v_cvt_pk_bf16_f32
__device__ __forceinline__ unsigned pk_bf16(float a, float b) {
  __hip_bfloat162 h = __float22bfloat162_rn(float2{a, b});
  unsigned r;
  memcpy(&r, &h, 4);
  return r;
}

// async global->LDS, 16 bytes per lane; LDS dest = wave-uniform base + lane*16
__device__ __forceinline__ void gload_lds16(const void* g, void* lds) {
  __builtin_amdgcn_global_load_lds(
      (const __attribute__((address_space(1))) unsigned int*)g,
      (__attribute__((address_space(3))) unsigned int*)lds, 16, 0, 0);
}

// ---------------- fused cast f32 -> bf16 for x + 5 weight matrices ----------------
__global__ __launch_bounds__(256) void cast_all(const float* __restrict__ x,
                                                const float* __restrict__ Wq,
                                                const float* __restrict__ Wk,
                                                const float* __restrict__ Wv,
                                                const float* __restrict__ Wo,
                                                const float* __restrict__ Wf,
                                                unsigned short* __restrict__ xb,
                                                unsigned short* __restrict__ Wqkv,
                                                unsigned short* __restrict__ Wob,
                                                unsigned short* __restrict__ Wfb) {
  int i = blockIdx.x * 256 + threadIdx.x;
  const float* src;
  unsigned short* dst;
  int j;
  if (i < 1048576)      { src = x;  dst = xb;             j = i; }
  else if (i < 1310720) { src = Wq; dst = Wqkv;           j = i - 1048576; }
  else if (i < 1572864) { src = Wk; dst = Wqkv + 1048576; j = i - 1310720; }
  else if (i < 1835008) { src = Wv; dst = Wqkv + 2097152; j = i - 1572864; }
  else if (i < 2097152) { src = Wo; dst = Wob;            j = i - 1835008; }
  else                  { src = Wf; dst = Wfb;            j = i - 2097152; }
  float4 v = ((const float4*)src)[j];
  u16x4 r = { f2bf(v.x), f2bf(v.y), f2bf(v.z), f2bf(v.w) };
  ((u16x4*)dst)[j] = r;
}

// ---------------- prep: maskadd (log2 domain) + QKV bias concat ----------------
__global__ __launch_bounds__(256) void prep_kernel(const int* __restrict__ mask,
                                                   const float* __restrict__ bq,
                                                   const float* __restrict__ bk,
                                                   const float* __restrict__ bv,
                                                   float* __restrict__ ma,
                                                   float* __restrict__ bcat) {
  int i = blockIdx.x * 256 + threadIdx.x;
  if (i < 4096) ma[i] = (mask[i] == 0) ? -1.4426950408889634e10f : 0.0f;
  int j = i - 4096;
  if (j >= 0 && j < 3072) {
    float v = (j < 1024) ? bq[j] : (j < 2048 ? bk[j - 1024] : bv[j - 2048]);
    bcat[j] = v;
  }
}

// ---------------- GEMM (m97 staging, 128x64 tile): C[M,N] = A[M,K]*W[N,K]^T + bias ----
// 4 waves, each owns a 32x64 output strip (acc[2][4]). Grid = (M/128, N/64).
// EPI: 0 = write bf16, 1 = write f32, 2 = gelu(exact) then f32
template <int EPI>
__global__ __launch_bounds__(256) void gemm_lds64(const unsigned short* __restrict__ A,
                                                  const unsigned short* __restrict__ W,
                                                  const float* __restrict__ bias,
                                                  void* __restrict__ Cout,
                                                  int M, int N, int K) {
  __shared__ unsigned short At[128 * 32];  // 8KB
  __shared__ unsigned short Bt[64 * 32];   // 4KB

  const int tid = threadIdx.x;
  const int w = tid >> 6, l = tid & 63;
  const int lr = l & 15, lq = l >> 4;
  const int row0 = blockIdx.x * 128;
  const int col0 = blockIdx.y * 64;

  const int srow = l >> 2;
  const int skoff = (l & 3) * 8;

  f32x4 acc[2][4] = {};

  const unsigned short* Abase = A + (row0 + srow) * (size_t)K + skoff;
  const unsigned short* Bbase = W + (col0 + srow) * (size_t)K + skoff;

  for (int kt = 0; kt < K; kt += 32) {
#pragma unroll
    for (int j = 0; j < 2; j++) {
      const int c = w * 2 + j;
      gload_lds16(Abase + (size_t)(c * 16) * K + kt, &At[c * 512]);
    }
    gload_lds16(Bbase + (size_t)(w * 16) * K + kt, &Bt[w * 512]);
    __syncthreads();

    short8 af[2], bfr[4];
#pragma unroll
    for (int m = 0; m < 2; m++)
      af[m] = *(const short8*)&At[(w * 32 + m * 16 + lr) * 32 + lq * 8];
#pragma unroll
    for (int n = 0; n < 4; n++)
      bfr[n] = *(const short8*)&Bt[(n * 16 + lr) * 32 + lq * 8];
#pragma unroll
    for (int m = 0; m < 2; m++)
#pragma unroll
      for (int n = 0; n < 4; n++)
        acc[m][n] = MFMA_BF16(af[m], bfr[n], acc[m][n]);
    __syncthreads();
  }

#pragma unroll
  for (int n = 0; n < 4; n++) {
    const int col = col0 + n * 16 + lr;
    const float bv = bias[col];
#pragma unroll
    for (int m = 0; m < 2; m++) {
      const int row = row0 + w * 32 + m * 16 + lq * 4;
#pragma unroll
      for (int r = 0; r < 4; r++) {
        float v = acc[m][n][r] + bv;
        if (EPI == 0) {
          ((unsigned short*)Cout)[(size_t)(row + r) * N + col] = f2bf(v);
        } else if (EPI == 1) {
          ((float*)Cout)[(size_t)(row + r) * N + col] = v;
        } else {
          float g = 0.5f * v * (1.0f + erff(v * 0.70710678118654752f));
          ((float*)Cout)[(size_t)(row + r) * N + col] = g;
        }
      }
    }
  }
}

// ---------------- V transpose: VT[(bh*64+d)][k] <- v-slab of qkv ----------------
__global__ __launch_bounds__(256) void vtrans_kernel(const unsigned short* __restrict__ qkv,
                                                     unsigned short* __restrict__ VT) {
  const int bh = blockIdx.x;   // 64
  const int kt = blockIdx.y;   // 16 tiles of 64 keys
  const int t = threadIdx.x;
  const int d = t & 63, kg = t >> 6;
  const unsigned short* basev =
      qkv + ((size_t)(bh >> 4) * 1024 + (bh & 15) * 64) * 3072 + 2048;
  const unsigned short* src = basev + (size_t)(kt * 4 + kg) * 3072 + d;
  unsigned short vals[16];
#pragma unroll
  for (int j = 0; j < 16; j++) vals[j] = src[j * 64];
  short8 v0, v1;
#pragma unroll
  for (int j = 0; j < 8; j++) { v0[j] = (short)vals[j]; v1[j] = (short)vals[8 + j]; }
  size_t dst = ((size_t)bh * 64 + d) * 1024 + kt * 64 + kg * 16;
  *(short8*)&VT[dst] = v0;
  *(short8*)&VT[dst + 8] = v1;
}

// ---------------- flash attention v9: shared LDS K/V staging (m97-style) ----------------
__global__ __launch_bounds__(256) void attn9_kernel(const unsigned short* __restrict__ qkv,
                                                    const unsigned short* __restrict__ VT,
                                                    const float* __restrict__ maskadd,
                                                    unsigned short* __restrict__ att) {
  __shared__ unsigned short Kt[2][2048];  // [buf][half c][32 key][32 shorts]
  __shared__ unsigned short Vt[2][2048];  // [buf][64 d][32 k-shorts]
  __shared__ float ma_lds[1024];
  __shared__ unsigned short Pl[4][2][640];  // per wave, per q-tile: [16 q][40]

  const int bh = blockIdx.x, b = bh >> 4, h = bh & 15;
  const int qb = blockIdx.y;
  const int tid = threadIdx.x, w = tid >> 6, l = tid & 63;
  const int lr = l & 15, lq = l >> 4;

  const unsigned short* baseq = qkv + ((size_t)b * 1024 + h * 64) * 3072;
  const unsigned short* basek = baseq + 1024;
  const unsigned short* vtb = VT + (size_t)bh * 64 * 1024;

  // staging roles (per thread)
  const int skey = (tid >> 2) & 31;
  const int skd = (tid >> 7) * 32 + (tid & 3) * 8;
  const int svd = tid >> 2;
  const int svc = (tid & 3) * 8;

  ((float4*)ma_lds)[tid] = ((const float4*)(maskadd + b * 1024))[tid];
  {
    const int pk = skey;
    gload_lds16(basek + (pk >> 4) * 3072 + (pk & 15) * 64 + skd, (char*)&Kt[0][0] + w * 1024);
    gload_lds16(vtb + (size_t)svd * 1024 + svc, (char*)&Vt[0][0] + w * 1024);
  }

  short8 qf[2][2];
  const int q0 = qb * 128 + w * 32;
#pragma unroll
  for (int t = 0; t < 2; t++) {
    int p = q0 + t * 16 + lr;
    const unsigned short* qa = baseq + (p >> 4) * 3072 + (p & 15) * 64;
    qf[t][0] = *(const short8*)(qa + lq * 8);
    qf[t][1] = *(const short8*)(qa + 32 + lq * 8);
  }
  __syncthreads();

  float m[2] = {-1e30f, -1e30f}, ll[2] = {0.f, 0.f};
  f32x4 o[2][4] = {};
  unsigned short* pw0 = &Pl[w][0][0];
  unsigned short* pw1 = &Pl[w][1][0];
  unsigned short* pws[2] = {pw0, pw1};
  constexpr float SC = 0.18033688011112042f;  // 0.125 * log2(e)

  int buf = 0;
#pragma unroll 1
  for (int kt = 0; kt < 32; kt++) {
    if (kt < 31) {
      const int pk = (kt + 1) * 32 + skey;
      gload_lds16(basek + (pk >> 4) * 3072 + (pk & 15) * 64 + skd,
                  (char*)&Kt[buf ^ 1][0] + w * 1024);
      gload_lds16(vtb + (size_t)svd * 1024 + (kt + 1) * 32 + svc,
                  (char*)&Vt[buf ^ 1][0] + w * 1024);
    }

    const unsigned short* KtL = &Kt[buf][0];
    const unsigned short* VtL = &Vt[buf][0];
    short8 vf[4];
#pragma unroll
    for (int n = 0; n < 4; n++)
      vf[n] = *(const short8*)&VtL[(n * 16 + lr) * 32 + lq * 8];

    const float4 mk0 = *(const float4*)&ma_lds[kt * 32 + lq * 4];
    const float4 mk1 = *(const float4*)&ma_lds[kt * 32 + 16 + lq * 4];
#pragma unroll
    for (int qt2 = 0; qt2 < 2; qt2++) {
      short8 kf00 = *(const short8*)&KtL[lr * 32 + lq * 8];
      short8 kf01 = *(const short8*)&KtL[1024 + lr * 32 + lq * 8];
      short8 kf10 = *(const short8*)&KtL[(16 + lr) * 32 + lq * 8];
      short8 kf11 = *(const short8*)&KtL[1024 + (16 + lr) * 32 + lq * 8];
      f32x4 s0 = {0.f, 0.f, 0.f, 0.f}, s1 = {0.f, 0.f, 0.f, 0.f};
      __builtin_amdgcn_s_setprio(1);
      s0 = MFMA_BF16(kf00, qf[qt2][0], s0);
      s0 = MFMA_BF16(kf01, qf[qt2][1], s0);
      s1 = MFMA_BF16(kf10, qf[qt2][0], s1);
      s1 = MFMA_BF16(kf11, qf[qt2][1], s1);
      __builtin_amdgcn_s_setprio(0);
      float sv[8];
#pragma unroll
      for (int r = 0; r < 4; r++) {
        sv[r]     = s0[r] * SC + ((const float*)&mk0)[r];
        sv[4 + r] = s1[r] * SC + ((const float*)&mk1)[r];
      }
      float t = fmaxf(fmaxf(fmaxf(sv[0], sv[1]), fmaxf(sv[2], sv[3])),
                      fmaxf(fmaxf(sv[4], sv[5]), fmaxf(sv[6], sv[7])));
      t = fmaxf(t, __shfl_xor(t, 16));
      t = fmaxf(t, __shfl_xor(t, 32));
      const float mn = fmaxf(m[qt2], t);
      if (!__all(mn == m[qt2])) {  // stable-skip (exact)
        const float sc = __builtin_amdgcn_exp2f(m[qt2] - mn);
        m[qt2] = mn;
        ll[qt2] *= sc;
        float scr[4];
#pragma unroll
        for (int r = 0; r < 4; r++) scr[r] = __shfl(sc, lq * 4 + r);
#pragma unroll
        for (int n = 0; n < 4; n++)
#pragma unroll
          for (int r = 0; r < 4; r++) o[qt2][n][r] *= scr[r];
      }
      float p[8], rs = 0.f;
#pragma unroll
      for (int i = 0; i < 8; i++) { p[i] = __builtin_amdgcn_exp2f(sv[i] - m[qt2]); rs += p[i]; }
      ll[qt2] += rs;  // deferred l-reduction (lane-partial)
      uint2 wa, wb;
      wa.x = pk_bf16(p[0], p[1]);
      wa.y = pk_bf16(p[2], p[3]);
      wb.x = pk_bf16(p[4], p[5]);
      wb.y = pk_bf16(p[6], p[7]);
      *(uint2*)&pws[qt2][lr * 40 + lq * 4] = wa;
      *(uint2*)&pws[qt2][lr * 40 + 16 + lq * 4] = wb;
    }
    asm volatile("s_waitcnt lgkmcnt(0)" ::: "memory");
#pragma unroll
    for (int qt2 = 0; qt2 < 2; qt2++) {
      const short8 pa = *(const short8*)&pws[qt2][lr * 40 + lq * 8];
      __builtin_amdgcn_s_setprio(1);
#pragma unroll
      for (int n = 0; n < 4; n++)
        o[qt2][n] = MFMA_BF16(pa, vf[n], o[qt2][n]);
      __builtin_amdgcn_s_setprio(0);
    }

    __syncthreads();
    buf ^= 1;
  }

#pragma unroll
  for (int qt2 = 0; qt2 < 2; qt2++) {
    float lf = ll[qt2];
    lf += __shfl_xor(lf, 16);
    lf += __shfl_xor(lf, 32);
    float inv[4];
#pragma unroll
    for (int r = 0; r < 4; r++) inv[r] = 1.0f / __shfl(lf, lq * 4 + r);
#pragma unroll
    for (int r = 0; r < 4; r++) {
      int q = q0 + qt2 * 16 + lq * 4 + r;
      size_t obase = ((size_t)b * 1024 + q) * 1024 + h * 64;
#pragma unroll
      for (int n = 0; n < 4; n++)
        att[obase + n * 16 + lr] = f2bf(o[qt2][n][r] * inv[r]);
    }
  }
}

// ---------------- LayerNorm kernels (fp32, E=1024, one row per block) ----------------
__global__ __launch_bounds__(256) void ln1_kernel(const float* __restrict__ x,
                                                  const float* __restrict__ attp,
                                                  const float* __restrict__ g,
                                                  const float* __restrict__ bt,
                                                  float* __restrict__ sf,
                                                  unsigned short* __restrict__ sb) {
  const int row = blockIdx.x, tid = threadIdx.x;
  float4 xv = ((const float4*)(x + row * 1024))[tid];
  float4 av = ((const float4*)(attp + row * 1024))[tid];
  float4 v = {xv.x + av.x, xv.y + av.y, xv.z + av.z, xv.w + av.w};
  float s = v.x + v.y + v.z + v.w;
  float sq = v.x * v.x + v.y * v.y + v.z * v.z + v.w * v.w;
#pragma unroll
  for (int off = 1; off < 64; off <<= 1) { s += __shfl_xor(s, off); sq += __shfl_xor(sq, off); }
  __shared__ float ws[8];
  int wv = tid >> 6, l = tid & 63;
  if (l == 0) { ws[wv] = s; ws[4 + wv] = sq; }
  __syncthreads();
  s = ws[0] + ws[1] + ws[2] + ws[3];
  sq = ws[4] + ws[5] + ws[6] + ws[7];
  float mean = s * (1.0f / 1024.0f);
  float var = sq * (1.0f / 1024.0f) - mean * mean;
  float rs = rsqrtf(var + 1e-5f);
  float4 gv = ((const float4*)g)[tid];
  float4 bv = ((const float4*)bt)[tid];
  float4 y;
  y.x = (v.x - mean) * rs * gv.x + bv.x;
  y.y = (v.y - mean) * rs * gv.y + bv.y;
  y.z = (v.z - mean) * rs * gv.z + bv.z;
  y.w = (v.w - mean) * rs * gv.w + bv.w;
  ((float4*)(sf + row * 1024))[tid] = y;
  u16x4 yb = { f2bf(y.x), f2bf(y.y), f2bf(y.z), f2bf(y.w) };
  ((u16x4*)(sb + row * 1024))[tid] = yb;
}

__global__ __launch_bounds__(256) void ln2_kernel(const float* __restrict__ skip,
                                                  const float* __restrict__ fcc,
                                                  const float* __restrict__ g,
                                                  const float* __restrict__ bt,
                                                  const float* __restrict__ x,
                                                  const float* __restrict__ alphap,
                                                  float* __restrict__ out) {
  const int row = blockIdx.x, tid = threadIdx.x;
  float4 sv = ((const float4*)(skip + row * 1024))[tid];
  float4 fv = ((const float4*)(fcc + row * 1024))[tid];
  float4 v = {sv.x + fv.x, sv.y + fv.y, sv.z + fv.z, sv.w + fv.w};
  float s = v.x + v.y + v.z + v.w;
  float sq = v.x * v.x + v.y * v.y + v.z * v.z + v.w * v.w;
#pragma unroll
  for (int off = 1; off < 64; off <<= 1) { s += __shfl_xor(s, off); sq += __shfl_xor(sq, off); }
  __shared__ float ws[8];
  int wv = tid >> 6, l = tid & 63;
  if (l == 0) { ws[wv] = s; ws[4 + wv] = sq; }
  __syncthreads();
  s = ws[0] + ws[1] + ws[2] + ws[3];
  sq = ws[4] + ws[5] + ws[6] + ws[7];
  float mean = s * (1.0f / 1024.0f);
  float var = sq * (1.0f / 1024.0f) - mean * mean;
  float rs = rsqrtf(var + 1e-5f);
  float4 gv = ((const float4*)g)[tid];
  float4 bv = ((const float4*)bt)[tid];
  float alpha = alphap[0];
  float beta = 1.0f - alpha;
  float4 xv = ((const float4*)(x + row * 1024))[tid];
  float4 y;
  y.x = xv.x * alpha + ((v.x - mean) * rs * gv.x + bv.x) * beta;
  y.y = xv.y * alpha + ((v.y - mean) * rs * gv.y + bv.y) * beta;
  y.z = xv.z * alpha + ((v.z - mean) * rs * gv.z + bv.z) * beta;
  y.w = xv.w * alpha + ((v.w - mean) * rs * gv.w + bv.w) * beta;
  ((float4*)(out + row * 1024))[tid] = y;
}

// ---------------- launch ----------------
extern "C" void kernel_launch(void* const* d_in, const int* in_sizes, int n_in,
                              void* d_out, int out_size, void* d_ws, size_t ws_size,
                              hipStream_t stream) {
  const float* x  = (const float*)d_in[0];
  const int* mask = (const int*)d_in[1];
  const float* Wq = (const float*)d_in[2];
  const float* bq = (const float*)d_in[3];
  const float* Wk = (const float*)d_in[4];
  const float* bk = (const float*)d_in[5];
  const float* Wv = (const float*)d_in[6];
  const float* bv = (const float*)d_in[7];
  const float* Wo = (const float*)d_in[8];
  const float* bo = (const float*)d_in[9];
  const float* g1 = (const float*)d_in[10];
  const float* b1 = (const float*)d_in[11];
  const float* Wf = (const float*)d_in[12];
  const float* bf = (const float*)d_in[13];
  const float* g2 = (const float*)d_in[14];
  const float* b2 = (const float*)d_in[15];
  const float* alpha = (const float*)d_in[16];
  float* out = (float*)d_out;

  char* ws = (char*)d_ws;
  size_t off = 0;
  unsigned short* xb   = (unsigned short*)(ws + off); off += 8388608;   // 4096x1024 bf16
  unsigned short* Wqkv = (unsigned short*)(ws + off); off += 6291456;   // 3072x1024 bf16
  unsigned short* Wob  = (unsigned short*)(ws + off); off += 2097152;
  unsigned short* Wfb  = (unsigned short*)(ws + off); off += 2097152;
  float* bcat          = (float*)(ws + off);          off += 12288;
  float* maf           = (float*)(ws + off);          off += 16384;     // maskadd [4][1024]
  unsigned short* qkvb = (unsigned short*)(ws + off); off += 25165824;  // 4096x3072 bf16
  unsigned short* attb = (unsigned short*)(ws + off); off += 8388608;
  float* tmp           = (float*)(ws + off);          off += 16777216;  // VT (attn) -> att@Wo -> fcc
  float* s1f           = (float*)(ws + off);          off += 16777216;
  unsigned short* s1b  = (unsigned short*)(ws + off); off += 8388608;

  unsigned short* VT = (unsigned short*)tmp;  // 8MB, used only during attention

  // fused casts + prep (maskadd + bias concat)
  cast_all<<<9216, 256, 0, stream>>>(x, Wq, Wk, Wv, Wo, Wf, xb, Wqkv, Wob, Wfb);
  prep_kernel<<<28, 256, 0, stream>>>(mask, bq, bk, bv, maf, bcat);

  // fused QKV GEMM: [4096,1024] x [3072,1024]^T -> bf16 [4096,3072]
  gemm_lds64<0><<<dim3(32, 48), 256, 0, stream>>>(xb, Wqkv, bcat, qkvb, 4096, 3072, 1024);

  // V transpose -> VT[(bh*64+d)][k]
  vtrans_kernel<<<dim3(64, 16), 256, 0, stream>>>(qkvb, VT);

  // attention -> att bf16 [4096,1024]
  attn9_kernel<<<dim3(64, 8), 256, 0, stream>>>(qkvb, VT, maf, attb);

  // O projection -> f32 tmp
  gemm_lds64<1><<<dim3(32, 16), 256, 0, stream>>>(attb, Wob, bo, tmp, 4096, 1024, 1024);

  // LN1: skip1 = LN(x + tmp); emits f32 + bf16
  ln1_kernel<<<4096, 256, 0, stream>>>(x, tmp, g1, b1, s1f, s1b);

  // FF GEMM + exact GELU -> f32 (reuse tmp)
  gemm_lds64<2><<<dim3(32, 16), 256, 0, stream>>>(s1b, Wfb, bf, tmp, 4096, 1024, 1024);

  // LN2 + final mix
  ln2_kernel<<<4096, 256, 0, stream>>>(s1f, tmp, g2, b2, x, alpha, out);
}

// Round 14
// 178.288 us; speedup vs baseline: 1.2147x; 1.0515x over previous
//
#include <hip/hip_runtime.h>
#include <hip/hip_bf16.h>
#include <string.h>

typedef __attribute__((ext_vector_type(8))) short short8;
typedef __attribute__((ext_vector_type(4))) float f32x4;
typedef __attribute__((ext_vector_type(4))) unsigned short u16x4;

#define MFMA_BF16(a, b, c) __builtin_amdgcn_mfma_f32_16x16x32_bf16((a), (b), (c), 0, 0, 0)

__device__ __forceinline__ unsigned short f2bf(float f) {
  unsigned int u = __builtin_bit_cast(unsigned int, f);
  u += 0x7fffu + ((u >> 16) & 1u);
  return (unsigned short)(u >> 16);
}

__device__ __forceinline__ float bf2f(unsigned short s) {
  unsigned int u = ((unsigned int)s) << 16;
  return __builtin_bit_cast(float, u);
}

// pack 2 f32 -> 1 dword of 2 bf16 (RTNE) via compiler-emitted v_cvt_pk_bf16_f32
__device__ __forceinline__ unsigned pk_bf16(float a, float b) {
  __hip_bfloat162 h = __float22bfloat162_rn(float2{a, b});
  unsigned r;
  memcpy(&r, &h, 4);
  return r;
}

// async global->LDS, 16 bytes per lane; LDS dest = wave-uniform base + lane*16
__device__ __forceinline__ void gload_lds16(const void* g, void* lds) {
  __builtin_amdgcn_global_load_lds(
      (const __attribute__((address_space(1))) unsigned int*)g,
      (__attribute__((address_space(3))) unsigned int*)lds, 16, 0, 0);
}

// ---------------- fused cast f32 -> bf16 for x + 5 weight matrices ----------------
__global__ __launch_bounds__(256) void cast_all(const float* __restrict__ x,
                                                const float* __restrict__ Wq,
                                                const float* __restrict__ Wk,
                                                const float* __restrict__ Wv,
                                                const float* __restrict__ Wo,
                                                const float* __restrict__ Wf,
                                                unsigned short* __restrict__ xb,
                                                unsigned short* __restrict__ Wqkv,
                                                unsigned short* __restrict__ Wob,
                                                unsigned short* __restrict__ Wfb) {
  int i = blockIdx.x * 256 + threadIdx.x;
  const float* src;
  unsigned short* dst;
  int j;
  if (i < 1048576)      { src = x;  dst = xb;             j = i; }
  else if (i < 1310720) { src = Wq; dst = Wqkv;           j = i - 1048576; }
  else if (i < 1572864) { src = Wk; dst = Wqkv + 1048576; j = i - 1310720; }
  else if (i < 1835008) { src = Wv; dst = Wqkv + 2097152; j = i - 1572864; }
  else if (i < 2097152) { src = Wo; dst = Wob;            j = i - 1835008; }
  else                  { src = Wf; dst = Wfb;            j = i - 2097152; }
  float4 v = ((const float4*)src)[j];
  u16x4 r = { f2bf(v.x), f2bf(v.y), f2bf(v.z), f2bf(v.w) };
  ((u16x4*)dst)[j] = r;
}

// ---------------- prep: maskadd (log2 domain) + QKV bias concat ----------------
__global__ __launch_bounds__(256) void prep_kernel(const int* __restrict__ mask,
                                                   const float* __restrict__ bq,
                                                   const float* __restrict__ bk,
                                                   const float* __restrict__ bv,
                                                   float* __restrict__ ma,
                                                   float* __restrict__ bcat) {
  int i = blockIdx.x * 256 + threadIdx.x;
  if (i < 4096) ma[i] = (mask[i] == 0) ? -1.4426950408889634e10f : 0.0f;
  int j = i - 4096;
  if (j >= 0 && j < 3072) {
    float v = (j < 1024) ? bq[j] : (j < 2048 ? bk[j - 1024] : bv[j - 2048]);
    bcat[j] = v;
  }
}

// ---------------- GEMM (m97 staging, 128x64 tile): C[M,N] = A[M,K]*W[N,K]^T + bias ----
// EPI: 0 = bf16, 1 = f32, 2 = gelu->f32, 3 = gelu->bf16
template <int EPI>
__global__ __launch_bounds__(256) void gemm_lds64(const unsigned short* __restrict__ A,
                                                  const unsigned short* __restrict__ W,
                                                  const float* __restrict__ bias,
                                                  void* __restrict__ Cout,
                                                  int M, int N, int K) {
  __shared__ unsigned short At[128 * 32];  // 8KB
  __shared__ unsigned short Bt[64 * 32];   // 4KB

  const int tid = threadIdx.x;
  const int w = tid >> 6, l = tid & 63;
  const int lr = l & 15, lq = l >> 4;
  const int row0 = blockIdx.x * 128;
  const int col0 = blockIdx.y * 64;

  const int srow = l >> 2;
  const int skoff = (l & 3) * 8;

  f32x4 acc[2][4] = {};

  const unsigned short* Abase = A + (row0 + srow) * (size_t)K + skoff;
  const unsigned short* Bbase = W + (col0 + srow) * (size_t)K + skoff;

  for (int kt = 0; kt < K; kt += 32) {
#pragma unroll
    for (int j = 0; j < 2; j++) {
      const int c = w * 2 + j;
      gload_lds16(Abase + (size_t)(c * 16) * K + kt, &At[c * 512]);
    }
    gload_lds16(Bbase + (size_t)(w * 16) * K + kt, &Bt[w * 512]);
    __syncthreads();

    short8 af[2], bfr[4];
#pragma unroll
    for (int m = 0; m < 2; m++)
      af[m] = *(const short8*)&At[(w * 32 + m * 16 + lr) * 32 + lq * 8];
#pragma unroll
    for (int n = 0; n < 4; n++)
      bfr[n] = *(const short8*)&Bt[(n * 16 + lr) * 32 + lq * 8];
#pragma unroll
    for (int m = 0; m < 2; m++)
#pragma unroll
      for (int n = 0; n < 4; n++)
        acc[m][n] = MFMA_BF16(af[m], bfr[n], acc[m][n]);
    __syncthreads();
  }

#pragma unroll
  for (int n = 0; n < 4; n++) {
    const int col = col0 + n * 16 + lr;
    const float bv = bias[col];
#pragma unroll
    for (int m = 0; m < 2; m++) {
      const int row = row0 + w * 32 + m * 16 + lq * 4;
#pragma unroll
      for (int r = 0; r < 4; r++) {
        float v = acc[m][n][r] + bv;
        if (EPI == 0) {
          ((unsigned short*)Cout)[(size_t)(row + r) * N + col] = f2bf(v);
        } else if (EPI == 1) {
          ((float*)Cout)[(size_t)(row + r) * N + col] = v;
        } else if (EPI == 2) {
          float g = 0.5f * v * (1.0f + erff(v * 0.70710678118654752f));
          ((float*)Cout)[(size_t)(row + r) * N + col] = g;
        } else {
          float g = 0.5f * v * (1.0f + erff(v * 0.70710678118654752f));
          ((unsigned short*)Cout)[(size_t)(row + r) * N + col] = f2bf(g);
        }
      }
    }
  }
}

// ---------------- V transpose: VT[(bh*64+d)][k] <- v-slab of qkv ----------------
__global__ __launch_bounds__(256) void vtrans_kernel(const unsigned short* __restrict__ qkv,
                                                     unsigned short* __restrict__ VT) {
  const int bh = blockIdx.x;
  const int kt = blockIdx.y;
  const int t = threadIdx.x;
  const int d = t & 63, kg = t >> 6;
  const unsigned short* basev =
      qkv + ((size_t)(bh >> 4) * 1024 + (bh & 15) * 64) * 3072 + 2048;
  const unsigned short* src = basev + (size_t)(kt * 4 + kg) * 3072 + d;
  unsigned short vals[16];
#pragma unroll
  for (int j = 0; j < 16; j++) vals[j] = src[j * 64];
  short8 v0, v1;
#pragma unroll
  for (int j = 0; j < 8; j++) { v0[j] = (short)vals[j]; v1[j] = (short)vals[8 + j]; }
  size_t dst = ((size_t)bh * 64 + d) * 1024 + kt * 64 + kg * 16;
  *(short8*)&VT[dst] = v0;
  *(short8*)&VT[dst + 8] = v1;
}

// ---------------- flash attention v10 ----------------
// 64-key stages (16 barriers), XOR-swizzled K/V LDS (T2, rule #21: linear dest +
// inverse-swizzled global source + swizzled read). Math identical to attn9.
__global__ __launch_bounds__(256) void attn10_kernel(const unsigned short* __restrict__ qkv,
                                                     const unsigned short* __restrict__ VT,
                                                     const float* __restrict__ maskadd,
                                                     unsigned short* __restrict__ att) {
  __shared__ unsigned short Kt[2][2][2048];  // [buf][sub][half][32 key][32 shorts]
  __shared__ unsigned short Vt[2][2][2048];  // [buf][sub][64 d][32 shorts]
  __shared__ float ma_lds[1024];
  __shared__ unsigned short Pl[4][2][640];

  const int bh = blockIdx.x, b = bh >> 4, h = bh & 15;
  const int qb = blockIdx.y;
  const int tid = threadIdx.x, w = tid >> 6, l = tid & 63;
  const int lr = l & 15, lq = l >> 4;

  const unsigned short* baseq = qkv + ((size_t)b * 1024 + h * 64) * 3072;
  const unsigned short* basek = baseq + 1024;
  const unsigned short* vtb = VT + (size_t)bh * 64 * 1024;

  // staging roles: K: (half, key, chunk); V: (d, chunk). Source chunk is XOR'd.
  const int skey = (tid >> 2) & 31;
  const int shalf = tid >> 7;
  const int skc = (tid & 3) ^ (skey & 3);   // inverse-swizzled source chunk
  const int svd = tid >> 2;
  const int svc = (tid & 3) ^ (svd & 3);

  ((float4*)ma_lds)[tid] = ((const float4*)(maskadd + b * 1024))[tid];
#pragma unroll
  for (int sub = 0; sub < 2; sub++) {
    const int pk = sub * 32 + skey;
    gload_lds16(basek + (pk >> 4) * 3072 + (pk & 15) * 64 + shalf * 32 + skc * 8,
                (char*)&Kt[0][sub][0] + w * 1024);
    gload_lds16(vtb + (size_t)svd * 1024 + sub * 32 + svc * 8,
                (char*)&Vt[0][sub][0] + w * 1024);
  }

  short8 qf[2][2];
  const int q0 = qb * 128 + w * 32;
#pragma unroll
  for (int t = 0; t < 2; t++) {
    int p = q0 + t * 16 + lr;
    const unsigned short* qa = baseq + (p >> 4) * 3072 + (p & 15) * 64;
    qf[t][0] = *(const short8*)(qa + lq * 8);
    qf[t][1] = *(const short8*)(qa + 32 + lq * 8);
  }
  __syncthreads();

  float m[2] = {-1e30f, -1e30f}, ll[2] = {0.f, 0.f};
  f32x4 o[2][4] = {};
  unsigned short* pws[2] = {&Pl[w][0][0], &Pl[w][1][0]};
  constexpr float SC = 0.18033688011112042f;  // 0.125 * log2(e)
  const int cx = (lq ^ (lr & 3)) * 8;         // swizzled read chunk (shorts)

  int buf = 0;
#pragma unroll 1
  for (int t2 = 0; t2 < 16; t2++) {
    if (t2 < 15) {
#pragma unroll
      for (int sub = 0; sub < 2; sub++) {
        const int pk = (t2 + 1) * 64 + sub * 32 + skey;
        gload_lds16(basek + (pk >> 4) * 3072 + (pk & 15) * 64 + shalf * 32 + skc * 8,
                    (char*)&Kt[buf ^ 1][sub][0] + w * 1024);
        gload_lds16(vtb + (size_t)svd * 1024 + (t2 + 1) * 64 + sub * 32 + svc * 8,
                    (char*)&Vt[buf ^ 1][sub][0] + w * 1024);
      }
    }

#pragma unroll
    for (int s = 0; s < 2; s++) {
      const int kcur = t2 * 2 + s;
      const unsigned short* KtL = &Kt[buf][s][0];
      const unsigned short* VtL = &Vt[buf][s][0];
      short8 vf[4];
#pragma unroll
      for (int n = 0; n < 4; n++)
        vf[n] = *(const short8*)&VtL[(n * 16 + lr) * 32 + cx];

      const float4 mk0 = *(const float4*)&ma_lds[kcur * 32 + lq * 4];
      const float4 mk1 = *(const float4*)&ma_lds[kcur * 32 + 16 + lq * 4];
#pragma unroll
      for (int qt2 = 0; qt2 < 2; qt2++) {
        short8 kf00 = *(const short8*)&KtL[lr * 32 + cx];
        short8 kf01 = *(const short8*)&KtL[1024 + lr * 32 + cx];
        short8 kf10 = *(const short8*)&KtL[(16 + lr) * 32 + cx];
        short8 kf11 = *(const short8*)&KtL[1024 + (16 + lr) * 32 + cx];
        f32x4 s0 = {0.f, 0.f, 0.f, 0.f}, s1 = {0.f, 0.f, 0.f, 0.f};
        __builtin_amdgcn_s_setprio(1);
        s0 = MFMA_BF16(kf00, qf[qt2][0], s0);
        s0 = MFMA_BF16(kf01, qf[qt2][1], s0);
        s1 = MFMA_BF16(kf10, qf[qt2][0], s1);
        s1 = MFMA_BF16(kf11, qf[qt2][1], s1);
        __builtin_amdgcn_s_setprio(0);
        float sv[8];
#pragma unroll
        for (int r = 0; r < 4; r++) {
          sv[r]     = s0[r] * SC + ((const float*)&mk0)[r];
          sv[4 + r] = s1[r] * SC + ((const float*)&mk1)[r];
        }
        float t = fmaxf(fmaxf(fmaxf(sv[0], sv[1]), fmaxf(sv[2], sv[3])),
                        fmaxf(fmaxf(sv[4], sv[5]), fmaxf(sv[6], sv[7])));
        t = fmaxf(t, __shfl_xor(t, 16));
        t = fmaxf(t, __shfl_xor(t, 32));
        const float mn = fmaxf(m[qt2], t);
        if (!__all(mn == m[qt2])) {  // stable-skip (exact)
          const float sc = __builtin_amdgcn_exp2f(m[qt2] - mn);
          m[qt2] = mn;
          ll[qt2] *= sc;
          float scr[4];
#pragma unroll
          for (int r = 0; r < 4; r++) scr[r] = __shfl(sc, lq * 4 + r);
#pragma unroll
          for (int n = 0; n < 4; n++)
#pragma unroll
            for (int r = 0; r < 4; r++) o[qt2][n][r] *= scr[r];
        }
        float p[8], rs = 0.f;
#pragma unroll
        for (int i = 0; i < 8; i++) { p[i] = __builtin_amdgcn_exp2f(sv[i] - m[qt2]); rs += p[i]; }
        ll[qt2] += rs;
        uint2 wa, wb;
        wa.x = pk_bf16(p[0], p[1]);
        wa.y = pk_bf16(p[2], p[3]);
        wb.x = pk_bf16(p[4], p[5]);
        wb.y = pk_bf16(p[6], p[7]);
        *(uint2*)&pws[qt2][lr * 40 + lq * 4] = wa;
        *(uint2*)&pws[qt2][lr * 40 + 16 + lq * 4] = wb;
      }
      asm volatile("s_waitcnt lgkmcnt(0)" ::: "memory");
#pragma unroll
      for (int qt2 = 0; qt2 < 2; qt2++) {
        const short8 pa = *(const short8*)&pws[qt2][lr * 40 + lq * 8];
        __builtin_amdgcn_s_setprio(1);
#pragma unroll
        for (int n = 0; n < 4; n++)
          o[qt2][n] = MFMA_BF16(pa, vf[n], o[qt2][n]);
        __builtin_amdgcn_s_setprio(0);
      }
    }

    __syncthreads();
    buf ^= 1;
  }

#pragma unroll
  for (int qt2 = 0; qt2 < 2; qt2++) {
    float lf = ll[qt2];
    lf += __shfl_xor(lf, 16);
    lf += __shfl_xor(lf, 32);
    float inv[4];
#pragma unroll
    for (int r = 0; r < 4; r++) inv[r] = 1.0f / __shfl(lf, lq * 4 + r);
#pragma unroll
    for (int r = 0; r < 4; r++) {
      int q = q0 + qt2 * 16 + lq * 4 + r;
      size_t obase = ((size_t)b * 1024 + q) * 1024 + h * 64;
#pragma unroll
      for (int n = 0; n < 4; n++)
        att[obase + n * 16 + lr] = f2bf(o[qt2][n][r] * inv[r]);
    }
  }
}

// ---------------- LayerNorm 1: skip1 = LN(x + att) -> bf16 only ----------------
__global__ __launch_bounds__(256) void ln1_kernel(const float* __restrict__ x,
                                                  const unsigned short* __restrict__ attp,
                                                  const float* __restrict__ g,
                                                  const float* __restrict__ bt,
                                                  unsigned short* __restrict__ sb) {
  const int row = blockIdx.x, tid = threadIdx.x;
  float4 xv = ((const float4*)(x + row * 1024))[tid];
  u16x4 ab = ((const u16x4*)(attp + row * 1024))[tid];
  float4 v = {xv.x + bf2f(ab[0]), xv.y + bf2f(ab[1]), xv.z + bf2f(ab[2]), xv.w + bf2f(ab[3])};
  float s = v.x + v.y + v.z + v.w;
  float sq = v.x * v.x + v.y * v.y + v.z * v.z + v.w * v.w;
#pragma unroll
  for (int off = 1; off < 64; off <<= 1) { s += __shfl_xor(s, off); sq += __shfl_xor(sq, off); }
  __shared__ float ws[8];
  int wv = tid >> 6, l = tid & 63;
  if (l == 0) { ws[wv] = s; ws[4 + wv] = sq; }
  __syncthreads();
  s = ws[0] + ws[1] + ws[2] + ws[3];
  sq = ws[4] + ws[5] + ws[6] + ws[7];
  float mean = s * (1.0f / 1024.0f);
  float var = sq * (1.0f / 1024.0f) - mean * mean;
  float rs = rsqrtf(var + 1e-5f);
  float4 gv = ((const float4*)g)[tid];
  float4 bv = ((const float4*)bt)[tid];
  u16x4 yb = { f2bf((v.x - mean) * rs * gv.x + bv.x),
               f2bf((v.y - mean) * rs * gv.y + bv.y),
               f2bf((v.z - mean) * rs * gv.z + bv.z),
               f2bf((v.w - mean) * rs * gv.w + bv.w) };
  ((u16x4*)(sb + row * 1024))[tid] = yb;
}

// ---------------- LayerNorm 2 + final mix (bf16 skip/fcc inputs) ----------------
__global__ __launch_bounds__(256) void ln2_kernel(const unsigned short* __restrict__ skip,
                                                  const unsigned short* __restrict__ fcc,
                                                  const float* __restrict__ g,
                                                  const float* __restrict__ bt,
                                                  const float* __restrict__ x,
                                                  const float* __restrict__ alphap,
                                                  float* __restrict__ out) {
  const int row = blockIdx.x, tid = threadIdx.x;
  u16x4 sb = ((const u16x4*)(skip + row * 1024))[tid];
  u16x4 fb = ((const u16x4*)(fcc + row * 1024))[tid];
  float4 v = {bf2f(sb[0]) + bf2f(fb[0]), bf2f(sb[1]) + bf2f(fb[1]),
              bf2f(sb[2]) + bf2f(fb[2]), bf2f(sb[3]) + bf2f(fb[3])};
  float s = v.x + v.y + v.z + v.w;
  float sq = v.x * v.x + v.y * v.y + v.z * v.z + v.w * v.w;
#pragma unroll
  for (int off = 1; off < 64; off <<= 1) { s += __shfl_xor(s, off); sq += __shfl_xor(sq, off); }
  __shared__ float ws[8];
  int wv = tid >> 6, l = tid & 63;
  if (l == 0) { ws[wv] = s; ws[4 + wv] = sq; }
  __syncthreads();
  s = ws[0] + ws[1] + ws[2] + ws[3];
  sq = ws[4] + ws[5] + ws[6] + ws[7];
  float mean = s * (1.0f / 1024.0f);
  float var = sq * (1.0f / 1024.0f) - mean * mean;
  float rs = rsqrtf(var + 1e-5f);
  float4 gv = ((const float4*)g)[tid];
  float4 bv = ((const float4*)bt)[tid];
  float alpha = alphap[0];
  float beta = 1.0f - alpha;
  float4 xv = ((const float4*)(x + row * 1024))[tid];
  float4 y;
  y.x = xv.x * alpha + ((v.x - mean) * rs * gv.x + bv.x) * beta;
  y.y = xv.y * alpha + ((v.y - mean) * rs * gv.y + bv.y) * beta;
  y.z = xv.z * alpha + ((v.z - mean) * rs * gv.z + bv.z) * beta;
  y.w = xv.w * alpha + ((v.w - mean) * rs * gv.w + bv.w) * beta;
  ((float4*)(out + row * 1024))[tid] = y;
}

// ---------------- launch ----------------
extern "C" void kernel_launch(void* const* d_in, const int* in_sizes, int n_in,
                              void* d_out, int out_size, void* d_ws, size_t ws_size,
                              hipStream_t stream) {
  const float* x  = (const float*)d_in[0];
  const int* mask = (const int*)d_in[1];
  const float* Wq = (const float*)d_in[2];
  const float* bq = (const float*)d_in[3];
  const float* Wk = (const float*)d_in[4];
  const float* bk = (const float*)d_in[5];
  const float* Wv = (const float*)d_in[6];
  const float* bv = (const float*)d_in[7];
  const float* Wo = (const float*)d_in[8];
  const float* bo = (const float*)d_in[9];
  const float* g1 = (const float*)d_in[10];
  const float* b1 = (const float*)d_in[11];
  const float* Wf = (const float*)d_in[12];
  const float* bf = (const float*)d_in[13];
  const float* g2 = (const float*)d_in[14];
  const float* b2 = (const float*)d_in[15];
  const float* alpha = (const float*)d_in[16];
  float* out = (float*)d_out;

  char* ws = (char*)d_ws;
  size_t off = 0;
  unsigned short* xb   = (unsigned short*)(ws + off); off += 8388608;   // 4096x1024 bf16
  unsigned short* Wqkv = (unsigned short*)(ws + off); off += 6291456;   // 3072x1024 bf16
  unsigned short* Wob  = (unsigned short*)(ws + off); off += 2097152;
  unsigned short* Wfb  = (unsigned short*)(ws + off); off += 2097152;
  float* bcat          = (float*)(ws + off);          off += 12288;
  float* maf           = (float*)(ws + off);          off += 16384;     // maskadd [4][1024]
  unsigned short* qkvb = (unsigned short*)(ws + off); off += 25165824;  // 4096x3072 bf16
  unsigned short* attb = (unsigned short*)(ws + off); off += 8388608;
  float* tmp           = (float*)(ws + off);          off += 16777216;  // VT/obf/fbf
  float* s1f           = (float*)(ws + off);          off += 16777216;  // (unused)
  unsigned short* s1b  = (unsigned short*)(ws + off); off += 8388608;
  (void)s1f;

  unsigned short* VT  = (unsigned short*)tmp;              // 8MB, attn phase
  unsigned short* obf = (unsigned short*)tmp;              // 8MB, O-proj out (after attn)
  unsigned short* fbf = (unsigned short*)tmp + 4194304;    // 8MB, FF out

  // fused casts + prep (maskadd + bias concat)
  cast_all<<<9216, 256, 0, stream>>>(x, Wq, Wk, Wv, Wo, Wf, xb, Wqkv, Wob, Wfb);
  prep_kernel<<<28, 256, 0, stream>>>(mask, bq, bk, bv, maf, bcat);

  // fused QKV GEMM: [4096,1024] x [3072,1024]^T -> bf16 [4096,3072]
  gemm_lds64<0><<<dim3(32, 48), 256, 0, stream>>>(xb, Wqkv, bcat, qkvb, 4096, 3072, 1024);

  // V transpose -> VT[(bh*64+d)][k]
  vtrans_kernel<<<dim3(64, 16), 256, 0, stream>>>(qkvb, VT);

  // attention -> att bf16 [4096,1024]
  attn10_kernel<<<dim3(64, 8), 256, 0, stream>>>(qkvb, VT, maf, attb);

  // O projection -> bf16 obf (overwrites VT region, which is dead now)
  gemm_lds64<0><<<dim3(32, 16), 256, 0, stream>>>(attb, Wob, bo, obf, 4096, 1024, 1024);

  // LN1: skip1 = LN(x + obf) -> bf16 s1b
  ln1_kernel<<<4096, 256, 0, stream>>>(x, obf, g1, b1, s1b);

  // FF GEMM + exact GELU -> bf16 fbf
  gemm_lds64<3><<<dim3(32, 16), 256, 0, stream>>>(s1b, Wfb, bf, fbf, 4096, 1024, 1024);

  // LN2 + final mix
  ln2_kernel<<<4096, 256, 0, stream>>>(s1b, fbf, g2, b2, x, alpha, out);
}